// Round 7
// baseline (394.714 us; speedup 1.0000x reference)
//
#include <hip/hip_runtime.h>

// x: [64, 256, 32, 32] f32 ; centroids: [256, 1024] ; cluster_size: [1024] ;
// centroids_avg: [256, 1024]
// N = 65536 rows, F = 256, K = 1024.  xf row n = (b*32 + w)*32 + h

#define DECAY 0.99f
#define EPSF 1e-5f
#define DELTA 0.05f

typedef _Float16 f16x8 __attribute__((ext_vector_type(8)));
typedef float f32x4 __attribute__((ext_vector_type(4)));

static __device__ __forceinline__ unsigned short h_bits(_Float16 h) {
  return __builtin_bit_cast(unsigned short, h);
}
static __device__ __forceinline__ float h_val(unsigned short u) {
  return (float)__builtin_bit_cast(_Float16, u);
}

// ---------------- centroid squared norms (fp32 exact) ----------------
__global__ void csq_kernel(const float* __restrict__ cent, float* __restrict__ csq) {
  int k0 = blockIdx.x * 64;
  int t = threadIdx.x;
  int kk = t & 63, cg = t >> 6;
  float s = 0.f;
  for (int c = cg; c < 256; c += 4) {
    float v = cent[(size_t)c * 1024 + k0 + kk];
    s += v * v;
  }
  __shared__ float red[4][64];
  red[cg][kk] = s;
  __syncthreads();
  if (t < 64) csq[k0 + t] = red[0][t] + red[1][t] + red[2][t] + red[3][t];
}

// ---------------- centroids -> packed fp16 B-frag layout ----------------
// ctp element for (k, f): colt=k>>4, lr=k&15, ks=f>>5, lg=(f>>3)&3, e=f&7
// half index = colt*4096 + ks*512 + lr*32 + lg*8 + e
// => a wave's (colt,ks) B-frag load is one contiguous 1 KB segment.
__global__ void centT_kernel(const float* __restrict__ cent, _Float16* __restrict__ ctp) {
  __shared__ float tl[32][33];
  int f0 = (blockIdx.x >> 5) * 32, k0 = (blockIdx.x & 31) * 32;
  int t = threadIdx.x;
#pragma unroll
  for (int i = 0; i < 4; ++i) {
    int fi = (t >> 5) + i * 8, ki = t & 31;
    tl[fi][ki] = cent[(size_t)(f0 + fi) * 1024 + k0 + ki];
  }
  __syncthreads();
#pragma unroll
  for (int i = 0; i < 4; ++i) {
    int ki = (t >> 5) + i * 8, fi = t & 31;
    int k = k0 + ki, f = f0 + fi;
    _Float16 h = (_Float16)tl[fi][ki];
    size_t idx = (size_t)(k >> 4) * 4096 + (size_t)(f >> 5) * 512 +
                 (size_t)(k & 15) * 32 + (size_t)((f >> 3) & 3) * 8 + (f & 7);
    ctp[idx] = h;
  }
}

// ---------------- transpose x -> xh/xl fp16 [65536][256] ----------------
__global__ void transpose_kernel(const float* __restrict__ x, _Float16* __restrict__ xh,
                                 _Float16* __restrict__ xl) {
  __shared__ float tile[64][65];
  int bid = blockIdx.x;
  int pt = bid & 15, ct = (bid >> 4) & 3, b = bid >> 6;
  int c0 = ct * 64, p0 = pt * 64;
  int t = threadIdx.x;
#pragma unroll
  for (int i = 0; i < 16; ++i) {
    int idx = t + i * 256;
    int ci = idx >> 6, pi = idx & 63;
    tile[ci][pi] = x[((size_t)(b * 256 + c0 + ci) << 10) + p0 + pi];
  }
  __syncthreads();
#pragma unroll
  for (int i = 0; i < 8; ++i) {
    int idx = t + i * 256;            // 2048 = 64 p x 32 c-pairs
    int pi = idx >> 5, cp = idx & 31;
    int p = p0 + pi;
    int r = ((p & 31) << 5) | (p >> 5);
    float v0 = tile[cp * 2][pi], v1 = tile[cp * 2 + 1][pi];
    _Float16 h0 = (_Float16)v0, h1 = (_Float16)v1;
    _Float16 l0 = (_Float16)(v0 - (float)h0), l1 = (_Float16)(v1 - (float)h1);
    unsigned int uh = (unsigned int)h_bits(h0) | ((unsigned int)h_bits(h1) << 16);
    unsigned int ul = (unsigned int)h_bits(l0) | ((unsigned int)h_bits(l1) << 16);
    size_t base = ((size_t)((b << 10) + r)) * 128 + ct * 32 + cp;
    ((unsigned int*)xh)[base] = uh;
    ((unsigned int*)xl)[base] = ul;
  }
}

// ---------------- MFMA distance + argmin + 2nd-best margin ----------------
// dist(n,k) = csq[k] - 2*dot;  dot = xh.ch + xl.ch = x.ch  (2x mfma 16x16x32 f16)
// error vs exact: 2|x.cl| (std ~9e-3) << DELTA=0.05 margin; gap<DELTA rows -> fixup.
// block: 32 rows x 1024 cols, 4 waves; wave w owns cols [256w, 256w+256).
// A in LDS XOR-swizzled; A and B register double-buffered (static rotation).
__global__ __launch_bounds__(256, 3) void mfma_argmin_kernel(
    const _Float16* __restrict__ xh, const _Float16* __restrict__ xl,
    const _Float16* __restrict__ ctp, const float* __restrict__ csq,
    int* __restrict__ ind, int* __restrict__ flaglist,
    unsigned int* __restrict__ flagcnt, unsigned int* __restrict__ counts) {
  __shared__ _Float16 Ah[32 * 256];  // 512 B/row, swizzled
  __shared__ _Float16 Al[32 * 256];
  __shared__ float csql[1024];
  __shared__ float red1[4][32], red2[4][32];
  __shared__ int redk[4][32];
  const int t = threadIdx.x;
  const int lane = t & 63, w = t >> 6;
  const int lr = lane & 15, lg = lane >> 4;
  const int n0 = blockIdx.x * 32;

#pragma unroll
  for (int i = 0; i < 4; ++i) csql[t + i * 256] = csq[t + i * 256];
#pragma unroll
  for (int i = 0; i < 4; ++i) {
    int idx = t + i * 256;            // 1024 = 32 rows x 32 16B-chunks
    int row = idx >> 5, c16 = (idx & 31) * 16;
    int sw = c16 ^ ((row & 7) << 4);
    *(f16x8*)((char*)Ah + row * 512 + sw) =
        *(const f16x8*)((const char*)xh + (size_t)(n0 + row) * 512 + c16);
  }
#pragma unroll
  for (int i = 0; i < 4; ++i) {
    int idx = t + i * 256;
    int row = idx >> 5, c16 = (idx & 31) * 16;
    int sw = c16 ^ ((row & 7) << 4);
    *(f16x8*)((char*)Al + row * 512 + sw) =
        *(const f16x8*)((const char*)xl + (size_t)(n0 + row) * 512 + c16);
  }
  __syncthreads();

  float b1[2][4], b2v[2][4];
  int bk[2][4];
#pragma unroll
  for (int rt = 0; rt < 2; ++rt)
#pragma unroll
    for (int rg = 0; rg < 4; ++rg) { b1[rt][rg] = 3.4e38f; b2v[rt][rg] = 3.4e38f; bk[rt][rg] = 0; }

  const int swz = (lr & 7) << 4;
  const int boff = (lr * 4 + lg) * 16;  // byte offset of this lane's frag in a 1KB chunk
#pragma unroll 1
  for (int ch = 0; ch < 4; ++ch) {
    const int ccb = w * 256 + ch * 64;
    const int colt0 = ccb >> 4;       // 4 col-tiles of 16
    f32x4 acc[4][2];                  // [ct][rt]
#pragma unroll
    for (int ct = 0; ct < 4; ++ct)
#pragma unroll
      for (int rt = 0; rt < 2; ++rt) acc[ct][rt] = (f32x4){0.f, 0.f, 0.f, 0.f};

    auto loadB = [&](f16x8* dst, int kss) {
#pragma unroll
      for (int ct = 0; ct < 4; ++ct)
        dst[ct] = *(const f16x8*)((const char*)ctp +
                                  (size_t)(colt0 + ct) * 8192 + kss * 1024 + boff);
    };
    auto loadA = [&](f16x8* dh, f16x8* dl, int kss) {
#pragma unroll
      for (int rt = 0; rt < 2; ++rt) {
        int off = (rt * 16 + lr) * 512 + ((kss * 64 + lg * 16) ^ swz);
        dh[rt] = *(const f16x8*)((const char*)Ah + off);
        dl[rt] = *(const f16x8*)((const char*)Al + off);
      }
    };
    auto domfma = [&](const f16x8* bh, const f16x8* ah, const f16x8* al) {
#pragma unroll
      for (int ct = 0; ct < 4; ++ct)
#pragma unroll
        for (int rt = 0; rt < 2; ++rt) {
          acc[ct][rt] = __builtin_amdgcn_mfma_f32_16x16x32_f16(ah[rt], bh[ct], acc[ct][rt], 0, 0, 0);
          acc[ct][rt] = __builtin_amdgcn_mfma_f32_16x16x32_f16(al[rt], bh[ct], acc[ct][rt], 0, 0, 0);
        }
    };

    // software pipeline: double-buffered A (LDS) and B (L2), static rotation
    f16x8 pb0[4], pb1[4], pa0h[2], pa0l[2], pa1h[2], pa1l[2];
    loadB(pb0, 0);
    loadA(pa0h, pa0l, 0);
#pragma unroll
    for (int ks = 0; ks < 8; ks += 2) {
      if (ks + 1 < 8) { loadB(pb1, ks + 1); loadA(pa1h, pa1l, ks + 1); }
      domfma(pb0, pa0h, pa0l);
      if (ks + 2 < 8) { loadB(pb0, ks + 2); loadA(pa0h, pa0l, ks + 2); }
      if (ks + 1 < 8) domfma(pb1, pa1h, pa1l);
    }
    // fold into running best / 2nd-best (cols ascend over time -> first-min tiebreak)
#pragma unroll
    for (int ct = 0; ct < 4; ++ct) {
      const int col = ccb + ct * 16 + lr;
      const float cq = csql[col];
#pragma unroll
      for (int rt = 0; rt < 2; ++rt)
#pragma unroll
        for (int rg = 0; rg < 4; ++rg) {
          float d = cq - 2.f * acc[ct][rt][rg];
          if (d < b1[rt][rg]) {
            b2v[rt][rg] = b1[rt][rg];
            b1[rt][rg] = d;
            bk[rt][rg] = col;
          } else if (d < b2v[rt][rg]) {
            b2v[rt][rg] = d;
          }
        }
    }
  }

  // reduce over the 16 k-lanes of each group
#pragma unroll
  for (int rt = 0; rt < 2; ++rt)
#pragma unroll
    for (int rg = 0; rg < 4; ++rg) {
      float v1 = b1[rt][rg], v2 = b2v[rt][rg];
      int kk = bk[rt][rg];
#pragma unroll
      for (int off = 8; off >= 1; off >>= 1) {
        float o1 = __shfl_xor(v1, off);
        int ok = __shfl_xor(kk, off);
        float o2 = __shfl_xor(v2, off);
        float nb2 = fminf(fmaxf(v1, o1), fminf(v2, o2));
        if (o1 < v1 || (o1 == v1 && ok < kk)) { v1 = o1; kk = ok; }
        v2 = nb2;
      }
      if (lr == 0) {
        int row = rt * 16 + lg * 4 + rg;
        red1[w][row] = v1;
        redk[w][row] = kk;
        red2[w][row] = v2;
      }
    }
  __syncthreads();
  if (t < 32) {
    float v1 = red1[0][t], v2 = red2[0][t];
    int kk = redk[0][t];
#pragma unroll
    for (int wi = 1; wi < 4; ++wi) {
      float o1 = red1[wi][t], o2 = red2[wi][t];
      int ok = redk[wi][t];
      float nb2 = fminf(fmaxf(v1, o1), fminf(v2, o2));
      if (o1 < v1 || (o1 == v1 && ok < kk)) { v1 = o1; kk = ok; }
      v2 = nb2;
    }
    ind[n0 + t] = kk;
    atomicAdd(&counts[kk], 1u);
    if (v2 - v1 < DELTA) {
      unsigned int p = atomicAdd(flagcnt, 1u);
      flaglist[p] = n0 + t;
    }
  }
}

// ---------------- exact fp32 re-argmin for low-margin rows ----------------
__global__ __launch_bounds__(256) void fixup_kernel(
    const _Float16* __restrict__ xh, const _Float16* __restrict__ xl,
    const float* __restrict__ cent, const float* __restrict__ csq,
    const int* __restrict__ flaglist, const unsigned int* __restrict__ flagcnt,
    int* __restrict__ ind, unsigned int* __restrict__ counts) {
  const int t = threadIdx.x;
  const int nf = (int)*flagcnt;
  __shared__ float xrow[256];
  __shared__ float rv[256];
  __shared__ int rk[256];
  for (int ii = blockIdx.x; ii < nf; ii += gridDim.x) {
    __syncthreads();
    int row = flaglist[ii];
    xrow[t] = (float)xh[(size_t)row * 256 + t] + (float)xl[(size_t)row * 256 + t];
    __syncthreads();
    float a0 = 0.f, a1 = 0.f, a2 = 0.f, a3 = 0.f;
#pragma unroll 8
    for (int f = 0; f < 256; ++f) {
      float xs = xrow[f];
      const float* cr = cent + (size_t)f * 1024 + t;
      a0 += xs * cr[0];
      a1 += xs * cr[256];
      a2 += xs * cr[512];
      a3 += xs * cr[768];
    }
    float bd = csq[t] - 2.f * a0;
    int bkk = t;
    float d1 = csq[t + 256] - 2.f * a1;
    if (d1 < bd) { bd = d1; bkk = t + 256; }
    float d2 = csq[t + 512] - 2.f * a2;
    if (d2 < bd) { bd = d2; bkk = t + 512; }
    float d3 = csq[t + 768] - 2.f * a3;
    if (d3 < bd) { bd = d3; bkk = t + 768; }
    rv[t] = bd;
    rk[t] = bkk;
    __syncthreads();
    for (int off = 128; off >= 1; off >>= 1) {
      if (t < off) {
        float ov = rv[t + off];
        int ok = rk[t + off];
        if (ov < rv[t] || (ov == rv[t] && ok < rk[t])) { rv[t] = ov; rk[t] = ok; }
      }
      __syncthreads();
    }
    if (t == 0) {
      int newk = rk[0];
      int oldk = ind[row];
      if (newk != oldk) {
        ind[row] = newk;
        atomicAdd(&counts[oldk], 0xFFFFFFFFu);  // -1
        atomicAdd(&counts[newk], 1u);
      }
    }
  }
}

// ---------------- single-wave: cluster-size EMA/Laplace norm + exclusive scan ----
__global__ __launch_bounds__(64) void csnorm_scan_kernel(
    const float* __restrict__ cs, const unsigned int* __restrict__ counts,
    float* __restrict__ icn, unsigned int* __restrict__ offsets,
    unsigned int* __restrict__ cursor) {
  const int t = threadIdx.x;  // 0..63, each owns 16 clusters
  unsigned int cl[16];
  float csl[16];
  unsigned int s = 0;
  float css = 0.f;
#pragma unroll
  for (int j = 0; j < 16; ++j) {
    cl[j] = counts[t * 16 + j];
    s += cl[j];
    csl[j] = cs[t * 16 + j];
    css += csl[j];
  }
  unsigned int incl = s;
#pragma unroll
  for (int off = 1; off < 64; off <<= 1) {
    unsigned int v = __shfl_up(incl, off);
    if (t >= off) incl += v;
  }
  unsigned int run = incl - s;  // exclusive prefix
  float tot = css;
#pragma unroll
  for (int off = 32; off >= 1; off >>= 1) tot += __shfl_xor(tot, off);
  const float n = DECAY * tot + (1.f - DECAY) * 65536.f;  // sum of new_cs (counts sum = N)
#pragma unroll
  for (int j = 0; j < 16; ++j) {
    int k = t * 16 + j;
    offsets[k] = run;
    cursor[k] = run;
    float ncs = DECAY * csl[j] + (1.f - DECAY) * (float)cl[j];
    float csn = (ncs + EPSF) / (n + 1024.f * EPSF) * n;
    icn[k] = 1.f / csn;
    run += cl[j];
  }
  if (t == 63) offsets[1024] = run;
}

// ---------------- scatter row ids into cluster-ordered list ----------------
__global__ void scatter_kernel(const int* __restrict__ ind, unsigned int* __restrict__ cursor,
                               int* __restrict__ rowlist) {
  int n = blockIdx.x * 256 + threadIdx.x;
  int k = ind[n];
  unsigned int pos = atomicAdd(&cursor[k], 1u);
  rowlist[pos] = n;
}

// ---------------- balanced segment-sum: position-partitioned + boundary flush ----
__global__ __launch_bounds__(256) void sumflush_kernel(
    const _Float16* __restrict__ xh, const _Float16* __restrict__ xl,
    const int* __restrict__ rowlist, const int* __restrict__ ind,
    float* __restrict__ sums) {
  __shared__ int rl[64];
  __shared__ int kl[64];
  const int t = threadIdx.x;
  const int sub = t >> 6, lane = t & 63;
  const int p0 = blockIdx.x * 64;
  if (t < 64) {
    int r = rowlist[p0 + t];
    rl[t] = r;
    kl[t] = ind[r];
  }
  __syncthreads();
  float a0 = 0.f, a1 = 0.f, a2 = 0.f, a3 = 0.f;
  int curk = kl[sub * 16];
#pragma unroll
  for (int i = 0; i < 16; ++i) {
    int p = sub * 16 + i;
    int k = kl[p];
    if (k != curk) {  // wave-uniform branch (k uniform across the wave)
      float* dst = &sums[(size_t)curk * 256 + lane * 4];
      atomicAdd(&dst[0], a0);
      atomicAdd(&dst[1], a1);
      atomicAdd(&dst[2], a2);
      atomicAdd(&dst[3], a3);
      a0 = a1 = a2 = a3 = 0.f;
      curk = k;
    }
    int r = rl[p];
    uint2 vh = *(const uint2*)&((const unsigned int*)xh)[(size_t)r * 128 + lane * 2];
    uint2 vl = *(const uint2*)&((const unsigned int*)xl)[(size_t)r * 128 + lane * 2];
    a0 += h_val((unsigned short)(vh.x & 0xFFFF)) + h_val((unsigned short)(vl.x & 0xFFFF));
    a1 += h_val((unsigned short)(vh.x >> 16)) + h_val((unsigned short)(vl.x >> 16));
    a2 += h_val((unsigned short)(vh.y & 0xFFFF)) + h_val((unsigned short)(vl.y & 0xFFFF));
    a3 += h_val((unsigned short)(vh.y >> 16)) + h_val((unsigned short)(vl.y >> 16));
  }
  float* dst = &sums[(size_t)curk * 256 + lane * 4];
  atomicAdd(&dst[0], a0);
  atomicAdd(&dst[1], a1);
  atomicAdd(&dst[2], a2);
  atomicAdd(&dst[3], a3);
}

// ---------------- centroid EMA + scale, [k][f] -> [f][k] transpose ----------------
__global__ __launch_bounds__(256) void newcentT_kernel(
    const float* __restrict__ sums, const float* __restrict__ avg,
    const float* __restrict__ icn, float* __restrict__ nc) {
  __shared__ float tl[32][33];
  const int t = threadIdx.x;
  const int k0 = (blockIdx.x & 31) * 32, f0 = (blockIdx.x >> 5) * 32;
#pragma unroll
  for (int i = 0; i < 4; ++i) {
    int ki = (t >> 5) + i * 8, fi = t & 31;
    tl[ki][fi] = sums[(size_t)(k0 + ki) * 256 + f0 + fi];
  }
  __syncthreads();
#pragma unroll
  for (int i = 0; i < 4; ++i) {
    int fi = (t >> 5) + i * 8, ki = t & 31;
    size_t idx = (size_t)(f0 + fi) * 1024 + k0 + ki;
    nc[idx] = (DECAY * avg[idx] + (1.f - DECAY) * tl[ki][fi]) * icn[k0 + ki];
  }
}

// ---------------- gather output: out[b][c][h][w] = nc[c][ind[n(b,w,h)]] ----------------
__global__ void gather_kernel(const float* __restrict__ nc, const int* __restrict__ ind,
                              float* __restrict__ out) {
  __shared__ int ip[1024];
  int b = blockIdx.x >> 3;
  int cg = (blockIdx.x & 7) * 32;
  int t = threadIdx.x;
#pragma unroll
  for (int j = 0; j < 4; ++j) {
    int p = t + j * 256;                 // p = h*32 + w
    int r = ((p & 31) << 5) | (p >> 5);  // r = w*32 + h
    ip[p] = ind[(b << 10) + r];
  }
  __syncthreads();
  for (int c = cg; c < cg + 32; ++c) {
    const float* row = nc + (size_t)c * 1024;
#pragma unroll
    for (int j = 0; j < 4; ++j) {
      int p = t + j * 256;
      out[((size_t)(b * 256 + c) << 10) + p] = row[ip[p]];
    }
  }
}

extern "C" void kernel_launch(void* const* d_in, const int* in_sizes, int n_in,
                              void* d_out, int out_size, void* d_ws, size_t ws_size,
                              hipStream_t stream) {
  const float* x = (const float*)d_in[0];
  const float* cent = (const float*)d_in[1];
  const float* cs = (const float*)d_in[2];
  const float* avg = (const float*)d_in[3];
  float* out = (float*)d_out;

  char* ws = (char*)d_ws;
  _Float16* xh = (_Float16*)ws;                              // 32 MB
  _Float16* xl = (_Float16*)(ws + 33554432);                 // 32 MB
  _Float16* ctp = (_Float16*)(ws + 67108864);                // 512 KB packed B
  float* nc = (float*)(ws + 67108864);                       // 1 MB (aliases ctp; disjoint lifetime)
  unsigned int* counts = (unsigned int*)(ws + 68157440);     // 4 KB
  unsigned int* flagcnt = (unsigned int*)(ws + 68161536);    // 4 KB
  float* csq = (float*)(ws + 68165632);                      // 4 KB
  float* icn = (float*)(ws + 68169728);                      // 4 KB
  unsigned int* offsets = (unsigned int*)(ws + 68173824);    // 8 KB (1025 used)
  unsigned int* cursor = (unsigned int*)(ws + 68182016);     // 4 KB
  int* ind = (int*)(ws + 68186112);                          // 256 KB
  int* flaglist = (int*)(ws + 68448256);                     // 256 KB (aliases rowlist; disjoint lifetime)
  int* rowlist = (int*)(ws + 68448256);
  float* sums = (float*)(ws + 68710400);                     // 1 MB [k][f]

  hipMemsetAsync(counts, 0, 8192, stream);   // counts + flagcnt
  hipMemsetAsync(sums, 0, 1048576, stream);  // sums

  csq_kernel<<<16, 256, 0, stream>>>(cent, csq);
  centT_kernel<<<256, 256, 0, stream>>>(cent, ctp);
  transpose_kernel<<<4096, 256, 0, stream>>>(x, xh, xl);
  mfma_argmin_kernel<<<2048, 256, 0, stream>>>(xh, xl, ctp, csq, ind, flaglist, flagcnt, counts);
  fixup_kernel<<<128, 256, 0, stream>>>(xh, xl, cent, csq, flaglist, flagcnt, ind, counts);
  csnorm_scan_kernel<<<1, 64, 0, stream>>>(cs, counts, icn, offsets, cursor);
  scatter_kernel<<<256, 256, 0, stream>>>(ind, cursor, rowlist);
  sumflush_kernel<<<1024, 256, 0, stream>>>(xh, xl, rowlist, ind, sums);
  newcentT_kernel<<<256, 256, 0, stream>>>(sums, avg, icn, nc);
  gather_kernel<<<512, 256, 0, stream>>>(nc, ind, out);
}

// Round 8
// 386.411 us; speedup vs baseline: 1.0215x; 1.0215x over previous
//
#include <hip/hip_runtime.h>

// x: [64, 256, 32, 32] f32 ; centroids: [256, 1024] ; cluster_size: [1024] ;
// centroids_avg: [256, 1024]
// N = 65536 rows, F = 256, K = 1024.  xf row n = (b*32 + w)*32 + h

#define DECAY 0.99f
#define EPSF 1e-5f
#define DELTA 0.05f

typedef _Float16 f16x8 __attribute__((ext_vector_type(8)));
typedef float f32x4 __attribute__((ext_vector_type(4)));

static __device__ __forceinline__ unsigned short h_bits(_Float16 h) {
  return __builtin_bit_cast(unsigned short, h);
}
static __device__ __forceinline__ float h_val(unsigned short u) {
  return (float)__builtin_bit_cast(_Float16, u);
}

// ---------------- centroid squared norms (fp32 exact) ----------------
__global__ void csq_kernel(const float* __restrict__ cent, float* __restrict__ csq) {
  int k0 = blockIdx.x * 64;
  int t = threadIdx.x;
  int kk = t & 63, cg = t >> 6;
  float s = 0.f;
  for (int c = cg; c < 256; c += 4) {
    float v = cent[(size_t)c * 1024 + k0 + kk];
    s += v * v;
  }
  __shared__ float red[4][64];
  red[cg][kk] = s;
  __syncthreads();
  if (t < 64) csq[k0 + t] = red[0][t] + red[1][t] + red[2][t] + red[3][t];
}

// ---------------- centroids -> packed fp16 B-frag layout ----------------
// ctp element for (k, f): colt=k>>4, lr=k&15, ks=f>>5, lg=(f>>3)&3, e=f&7
// half index = colt*4096 + ks*512 + lr*32 + lg*8 + e
// => a wave's (colt,ks) B-frag load is one contiguous 1 KB segment.
__global__ void centT_kernel(const float* __restrict__ cent, _Float16* __restrict__ ctp) {
  __shared__ float tl[32][33];
  int f0 = (blockIdx.x >> 5) * 32, k0 = (blockIdx.x & 31) * 32;
  int t = threadIdx.x;
#pragma unroll
  for (int i = 0; i < 4; ++i) {
    int fi = (t >> 5) + i * 8, ki = t & 31;
    tl[fi][ki] = cent[(size_t)(f0 + fi) * 1024 + k0 + ki];
  }
  __syncthreads();
#pragma unroll
  for (int i = 0; i < 4; ++i) {
    int ki = (t >> 5) + i * 8, fi = t & 31;
    int k = k0 + ki, f = f0 + fi;
    _Float16 h = (_Float16)tl[fi][ki];
    size_t idx = (size_t)(k >> 4) * 4096 + (size_t)(f >> 5) * 512 +
                 (size_t)(k & 15) * 32 + (size_t)((f >> 3) & 3) * 8 + (f & 7);
    ctp[idx] = h;
  }
}

// ---------------- transpose x -> xh/xl fp16 [65536][256] ----------------
__global__ void transpose_kernel(const float* __restrict__ x, _Float16* __restrict__ xh,
                                 _Float16* __restrict__ xl) {
  __shared__ float tile[64][65];
  int bid = blockIdx.x;
  int pt = bid & 15, ct = (bid >> 4) & 3, b = bid >> 6;
  int c0 = ct * 64, p0 = pt * 64;
  int t = threadIdx.x;
#pragma unroll
  for (int i = 0; i < 16; ++i) {
    int idx = t + i * 256;
    int ci = idx >> 6, pi = idx & 63;
    tile[ci][pi] = x[((size_t)(b * 256 + c0 + ci) << 10) + p0 + pi];
  }
  __syncthreads();
#pragma unroll
  for (int i = 0; i < 8; ++i) {
    int idx = t + i * 256;            // 2048 = 64 p x 32 c-pairs
    int pi = idx >> 5, cp = idx & 31;
    int p = p0 + pi;
    int r = ((p & 31) << 5) | (p >> 5);
    float v0 = tile[cp * 2][pi], v1 = tile[cp * 2 + 1][pi];
    _Float16 h0 = (_Float16)v0, h1 = (_Float16)v1;
    _Float16 l0 = (_Float16)(v0 - (float)h0), l1 = (_Float16)(v1 - (float)h1);
    unsigned int uh = (unsigned int)h_bits(h0) | ((unsigned int)h_bits(h1) << 16);
    unsigned int ul = (unsigned int)h_bits(l0) | ((unsigned int)h_bits(l1) << 16);
    size_t base = ((size_t)((b << 10) + r)) * 128 + ct * 32 + cp;
    ((unsigned int*)xh)[base] = uh;
    ((unsigned int*)xl)[base] = ul;
  }
}

// ---------------- MFMA distance + argmin + 2nd-best margin ----------------
// dist(n,k) = csq[k] - 2*xh.ch  (1x mfma 16x16x32 f16 per tile-combo)
// dropped terms (xl.ch + x.cl): |err| std ~6e-3 << DELTA=0.05; gap<DELTA -> exact fixup.
// block: 64 rows x 1024 cols, 4 waves; wave w owns cols [256w, 256w+256), rt=4.
// Ah in LDS XOR-swizzled; B register double-buffered, inline static rotation.
__global__ __launch_bounds__(256, 3) void mfma_argmin_kernel(
    const _Float16* __restrict__ xh, const _Float16* __restrict__ ctp,
    const float* __restrict__ csq, int* __restrict__ ind,
    int* __restrict__ flaglist, unsigned int* __restrict__ flagcnt,
    unsigned int* __restrict__ counts) {
  __shared__ _Float16 Ah[64 * 256];  // 512 B/row, swizzled
  __shared__ float csql[1024];
  __shared__ float red1[4][64], red2[4][64];
  __shared__ int redk[4][64];
  const int t = threadIdx.x;
  const int lane = t & 63, w = t >> 6;
  const int lr = lane & 15, lg = lane >> 4;
  const int n0 = blockIdx.x * 64;

#pragma unroll
  for (int i = 0; i < 4; ++i) csql[t + i * 256] = csq[t + i * 256];
#pragma unroll
  for (int i = 0; i < 8; ++i) {
    int idx = t + i * 256;            // 2048 = 64 rows x 32 16B-chunks
    int row = idx >> 5, c16 = (idx & 31) * 16;
    int sw = c16 ^ ((row & 7) << 4);
    *(f16x8*)((char*)Ah + row * 512 + sw) =
        *(const f16x8*)((const char*)xh + (size_t)(n0 + row) * 512 + c16);
  }
  __syncthreads();

  float b1[4][4], b2v[4][4];
  int bk[4][4];
#pragma unroll
  for (int rt = 0; rt < 4; ++rt)
#pragma unroll
    for (int rg = 0; rg < 4; ++rg) { b1[rt][rg] = 3.4e38f; b2v[rt][rg] = 3.4e38f; bk[rt][rg] = 0; }

  const int swz = (lr & 7) << 4;
  const int boff = (lr * 4 + lg) * 16;  // byte offset of this lane's frag in a 1KB chunk
#pragma unroll 1
  for (int ch = 0; ch < 4; ++ch) {
    const int ccb = w * 256 + ch * 64;
    const size_t cbase = (size_t)(ccb >> 4) * 8192 + boff;  // 4 col-tiles of 16, 8KB apart
    f32x4 acc[4][4];                  // [ct][rt]
#pragma unroll
    for (int ct = 0; ct < 4; ++ct)
#pragma unroll
      for (int rt = 0; rt < 4; ++rt) acc[ct][rt] = (f32x4){0.f, 0.f, 0.f, 0.f};

    f16x8 pb0[4], pb1[4], ah[4];
    // prologue: B for ks=0
#pragma unroll
    for (int ct = 0; ct < 4; ++ct)
      pb0[ct] = *(const f16x8*)((const char*)ctp + cbase + (size_t)ct * 8192);
#pragma unroll
    for (int ks2 = 0; ks2 < 4; ++ks2) {
      const int ksA = ks2 * 2, ksB = ks2 * 2 + 1;
      // prefetch B for ksB (hides under ksA's MFMA)
#pragma unroll
      for (int ct = 0; ct < 4; ++ct)
        pb1[ct] = *(const f16x8*)((const char*)ctp + cbase + (size_t)ct * 8192 + ksB * 1024);
#pragma unroll
      for (int rt = 0; rt < 4; ++rt)
        ah[rt] = *(const f16x8*)((const char*)Ah + (rt * 16 + lr) * 512 + ((ksA * 64 + lg * 16) ^ swz));
#pragma unroll
      for (int ct = 0; ct < 4; ++ct)
#pragma unroll
        for (int rt = 0; rt < 4; ++rt)
          acc[ct][rt] = __builtin_amdgcn_mfma_f32_16x16x32_f16(ah[rt], pb0[ct], acc[ct][rt], 0, 0, 0);
      if (ks2 < 3) {  // static under full unroll: prefetch B for ksA+2
#pragma unroll
        for (int ct = 0; ct < 4; ++ct)
          pb0[ct] = *(const f16x8*)((const char*)ctp + cbase + (size_t)ct * 8192 + (ksA + 2) * 1024);
      }
#pragma unroll
      for (int rt = 0; rt < 4; ++rt)
        ah[rt] = *(const f16x8*)((const char*)Ah + (rt * 16 + lr) * 512 + ((ksB * 64 + lg * 16) ^ swz));
#pragma unroll
      for (int ct = 0; ct < 4; ++ct)
#pragma unroll
        for (int rt = 0; rt < 4; ++rt)
          acc[ct][rt] = __builtin_amdgcn_mfma_f32_16x16x32_f16(ah[rt], pb1[ct], acc[ct][rt], 0, 0, 0);
    }
    // fold into running best / 2nd-best (cols ascend over time -> first-min tiebreak)
#pragma unroll
    for (int ct = 0; ct < 4; ++ct) {
      const int col = ccb + ct * 16 + lr;
      const float cq = csql[col];
#pragma unroll
      for (int rt = 0; rt < 4; ++rt)
#pragma unroll
        for (int rg = 0; rg < 4; ++rg) {
          float d = cq - 2.f * acc[ct][rt][rg];
          if (d < b1[rt][rg]) {
            b2v[rt][rg] = b1[rt][rg];
            b1[rt][rg] = d;
            bk[rt][rg] = col;
          } else if (d < b2v[rt][rg]) {
            b2v[rt][rg] = d;
          }
        }
    }
  }

  // reduce over the 16 k-lanes of each group
#pragma unroll
  for (int rt = 0; rt < 4; ++rt)
#pragma unroll
    for (int rg = 0; rg < 4; ++rg) {
      float v1 = b1[rt][rg], v2 = b2v[rt][rg];
      int kk = bk[rt][rg];
#pragma unroll
      for (int off = 8; off >= 1; off >>= 1) {
        float o1 = __shfl_xor(v1, off);
        int ok = __shfl_xor(kk, off);
        float o2 = __shfl_xor(v2, off);
        float nb2 = fminf(fmaxf(v1, o1), fminf(v2, o2));
        if (o1 < v1 || (o1 == v1 && ok < kk)) { v1 = o1; kk = ok; }
        v2 = nb2;
      }
      if (lr == 0) {
        int row = rt * 16 + lg * 4 + rg;
        red1[w][row] = v1;
        redk[w][row] = kk;
        red2[w][row] = v2;
      }
    }
  __syncthreads();
  if (t < 64) {
    float v1 = red1[0][t], v2 = red2[0][t];
    int kk = redk[0][t];
#pragma unroll
    for (int wi = 1; wi < 4; ++wi) {
      float o1 = red1[wi][t], o2 = red2[wi][t];
      int ok = redk[wi][t];
      float nb2 = fminf(fmaxf(v1, o1), fminf(v2, o2));
      if (o1 < v1 || (o1 == v1 && ok < kk)) { v1 = o1; kk = ok; }
      v2 = nb2;
    }
    ind[n0 + t] = kk;
    atomicAdd(&counts[kk], 1u);
    if (v2 - v1 < DELTA) {
      unsigned int p = atomicAdd(flagcnt, 1u);
      flaglist[p] = n0 + t;
    }
  }
}

// ---------------- exact fp32 re-argmin for low-margin rows ----------------
__global__ __launch_bounds__(256) void fixup_kernel(
    const _Float16* __restrict__ xh, const _Float16* __restrict__ xl,
    const float* __restrict__ cent, const float* __restrict__ csq,
    const int* __restrict__ flaglist, const unsigned int* __restrict__ flagcnt,
    int* __restrict__ ind, unsigned int* __restrict__ counts) {
  const int t = threadIdx.x;
  const int nf = (int)*flagcnt;
  __shared__ float xrow[256];
  __shared__ float rv[256];
  __shared__ int rk[256];
  for (int ii = blockIdx.x; ii < nf; ii += gridDim.x) {
    __syncthreads();
    int row = flaglist[ii];
    xrow[t] = (float)xh[(size_t)row * 256 + t] + (float)xl[(size_t)row * 256 + t];
    __syncthreads();
    float a0 = 0.f, a1 = 0.f, a2 = 0.f, a3 = 0.f;
#pragma unroll 8
    for (int f = 0; f < 256; ++f) {
      float xs = xrow[f];
      const float* cr = cent + (size_t)f * 1024 + t;
      a0 += xs * cr[0];
      a1 += xs * cr[256];
      a2 += xs * cr[512];
      a3 += xs * cr[768];
    }
    float bd = csq[t] - 2.f * a0;
    int bkk = t;
    float d1 = csq[t + 256] - 2.f * a1;
    if (d1 < bd) { bd = d1; bkk = t + 256; }
    float d2 = csq[t + 512] - 2.f * a2;
    if (d2 < bd) { bd = d2; bkk = t + 512; }
    float d3 = csq[t + 768] - 2.f * a3;
    if (d3 < bd) { bd = d3; bkk = t + 768; }
    rv[t] = bd;
    rk[t] = bkk;
    __syncthreads();
    for (int off = 128; off >= 1; off >>= 1) {
      if (t < off) {
        float ov = rv[t + off];
        int ok = rk[t + off];
        if (ov < rv[t] || (ov == rv[t] && ok < rk[t])) { rv[t] = ov; rk[t] = ok; }
      }
      __syncthreads();
    }
    if (t == 0) {
      int newk = rk[0];
      int oldk = ind[row];
      if (newk != oldk) {
        ind[row] = newk;
        atomicAdd(&counts[oldk], 0xFFFFFFFFu);  // -1
        atomicAdd(&counts[newk], 1u);
      }
    }
  }
}

// ---------------- single-wave: cluster-size EMA/Laplace norm + exclusive scan ----
__global__ __launch_bounds__(64) void csnorm_scan_kernel(
    const float* __restrict__ cs, const unsigned int* __restrict__ counts,
    float* __restrict__ icn, unsigned int* __restrict__ offsets,
    unsigned int* __restrict__ cursor) {
  const int t = threadIdx.x;  // 0..63, each owns 16 clusters
  unsigned int cl[16];
  float csl[16];
  unsigned int s = 0;
  float css = 0.f;
#pragma unroll
  for (int j = 0; j < 16; ++j) {
    cl[j] = counts[t * 16 + j];
    s += cl[j];
    csl[j] = cs[t * 16 + j];
    css += csl[j];
  }
  unsigned int incl = s;
#pragma unroll
  for (int off = 1; off < 64; off <<= 1) {
    unsigned int v = __shfl_up(incl, off);
    if (t >= off) incl += v;
  }
  unsigned int run = incl - s;  // exclusive prefix
  float tot = css;
#pragma unroll
  for (int off = 32; off >= 1; off >>= 1) tot += __shfl_xor(tot, off);
  const float n = DECAY * tot + (1.f - DECAY) * 65536.f;  // sum of new_cs (counts sum = N)
#pragma unroll
  for (int j = 0; j < 16; ++j) {
    int k = t * 16 + j;
    offsets[k] = run;
    cursor[k] = run;
    float ncs = DECAY * csl[j] + (1.f - DECAY) * (float)cl[j];
    float csn = (ncs + EPSF) / (n + 1024.f * EPSF) * n;
    icn[k] = 1.f / csn;
    run += cl[j];
  }
  if (t == 63) offsets[1024] = run;
}

// ---------------- scatter row ids into cluster-ordered list ----------------
__global__ void scatter_kernel(const int* __restrict__ ind, unsigned int* __restrict__ cursor,
                               int* __restrict__ rowlist) {
  int n = blockIdx.x * 256 + threadIdx.x;
  int k = ind[n];
  unsigned int pos = atomicAdd(&cursor[k], 1u);
  rowlist[pos] = n;
}

// ---------------- balanced segment-sum: position-partitioned + boundary flush ----
__global__ __launch_bounds__(256) void sumflush_kernel(
    const _Float16* __restrict__ xh, const _Float16* __restrict__ xl,
    const int* __restrict__ rowlist, const int* __restrict__ ind,
    float* __restrict__ sums) {
  __shared__ int rl[64];
  __shared__ int kl[64];
  const int t = threadIdx.x;
  const int sub = t >> 6, lane = t & 63;
  const int p0 = blockIdx.x * 64;
  if (t < 64) {
    int r = rowlist[p0 + t];
    rl[t] = r;
    kl[t] = ind[r];
  }
  __syncthreads();
  float a0 = 0.f, a1 = 0.f, a2 = 0.f, a3 = 0.f;
  int curk = kl[sub * 16];
#pragma unroll
  for (int i = 0; i < 16; ++i) {
    int p = sub * 16 + i;
    int k = kl[p];
    if (k != curk) {  // wave-uniform branch (k uniform across the wave)
      float* dst = &sums[(size_t)curk * 256 + lane * 4];
      atomicAdd(&dst[0], a0);
      atomicAdd(&dst[1], a1);
      atomicAdd(&dst[2], a2);
      atomicAdd(&dst[3], a3);
      a0 = a1 = a2 = a3 = 0.f;
      curk = k;
    }
    int r = rl[p];
    uint2 vh = *(const uint2*)&((const unsigned int*)xh)[(size_t)r * 128 + lane * 2];
    uint2 vl = *(const uint2*)&((const unsigned int*)xl)[(size_t)r * 128 + lane * 2];
    a0 += h_val((unsigned short)(vh.x & 0xFFFF)) + h_val((unsigned short)(vl.x & 0xFFFF));
    a1 += h_val((unsigned short)(vh.x >> 16)) + h_val((unsigned short)(vl.x >> 16));
    a2 += h_val((unsigned short)(vh.y & 0xFFFF)) + h_val((unsigned short)(vl.y & 0xFFFF));
    a3 += h_val((unsigned short)(vh.y >> 16)) + h_val((unsigned short)(vl.y >> 16));
  }
  float* dst = &sums[(size_t)curk * 256 + lane * 4];
  atomicAdd(&dst[0], a0);
  atomicAdd(&dst[1], a1);
  atomicAdd(&dst[2], a2);
  atomicAdd(&dst[3], a3);
}

// ---------------- centroid EMA + scale, [k][f] -> [f][k] transpose ----------------
__global__ __launch_bounds__(256) void newcentT_kernel(
    const float* __restrict__ sums, const float* __restrict__ avg,
    const float* __restrict__ icn, float* __restrict__ nc) {
  __shared__ float tl[32][33];
  const int t = threadIdx.x;
  const int k0 = (blockIdx.x & 31) * 32, f0 = (blockIdx.x >> 5) * 32;
#pragma unroll
  for (int i = 0; i < 4; ++i) {
    int ki = (t >> 5) + i * 8, fi = t & 31;
    tl[ki][fi] = sums[(size_t)(k0 + ki) * 256 + f0 + fi];
  }
  __syncthreads();
#pragma unroll
  for (int i = 0; i < 4; ++i) {
    int fi = (t >> 5) + i * 8, ki = t & 31;
    size_t idx = (size_t)(f0 + fi) * 1024 + k0 + ki;
    nc[idx] = (DECAY * avg[idx] + (1.f - DECAY) * tl[ki][fi]) * icn[k0 + ki];
  }
}

// ---------------- gather output: out[b][c][h][w] = nc[c][ind[n(b,w,h)]] ----------------
__global__ void gather_kernel(const float* __restrict__ nc, const int* __restrict__ ind,
                              float* __restrict__ out) {
  __shared__ int ip[1024];
  int b = blockIdx.x >> 3;
  int cg = (blockIdx.x & 7) * 32;
  int t = threadIdx.x;
#pragma unroll
  for (int j = 0; j < 4; ++j) {
    int p = t + j * 256;                 // p = h*32 + w
    int r = ((p & 31) << 5) | (p >> 5);  // r = w*32 + h
    ip[p] = ind[(b << 10) + r];
  }
  __syncthreads();
  for (int c = cg; c < cg + 32; ++c) {
    const float* row = nc + (size_t)c * 1024;
#pragma unroll
    for (int j = 0; j < 4; ++j) {
      int p = t + j * 256;
      out[((size_t)(b * 256 + c) << 10) + p] = row[ip[p]];
    }
  }
}

extern "C" void kernel_launch(void* const* d_in, const int* in_sizes, int n_in,
                              void* d_out, int out_size, void* d_ws, size_t ws_size,
                              hipStream_t stream) {
  const float* x = (const float*)d_in[0];
  const float* cent = (const float*)d_in[1];
  const float* cs = (const float*)d_in[2];
  const float* avg = (const float*)d_in[3];
  float* out = (float*)d_out;

  char* ws = (char*)d_ws;
  _Float16* xh = (_Float16*)ws;                              // 32 MB
  _Float16* xl = (_Float16*)(ws + 33554432);                 // 32 MB
  _Float16* ctp = (_Float16*)(ws + 67108864);                // 512 KB packed B
  float* nc = (float*)(ws + 67108864);                       // 1 MB (aliases ctp; disjoint lifetime)
  unsigned int* counts = (unsigned int*)(ws + 68157440);     // 4 KB
  unsigned int* flagcnt = (unsigned int*)(ws + 68161536);    // 4 KB
  float* csq = (float*)(ws + 68165632);                      // 4 KB
  float* icn = (float*)(ws + 68169728);                      // 4 KB
  unsigned int* offsets = (unsigned int*)(ws + 68173824);    // 8 KB (1025 used)
  unsigned int* cursor = (unsigned int*)(ws + 68182016);     // 4 KB
  int* ind = (int*)(ws + 68186112);                          // 256 KB
  int* flaglist = (int*)(ws + 68448256);                     // 256 KB (aliases rowlist; disjoint lifetime)
  int* rowlist = (int*)(ws + 68448256);
  float* sums = (float*)(ws + 68710400);                     // 1 MB [k][f]

  hipMemsetAsync(counts, 0, 8192, stream);   // counts + flagcnt
  hipMemsetAsync(sums, 0, 1048576, stream);  // sums

  csq_kernel<<<16, 256, 0, stream>>>(cent, csq);
  centT_kernel<<<256, 256, 0, stream>>>(cent, ctp);
  transpose_kernel<<<4096, 256, 0, stream>>>(x, xh, xl);
  mfma_argmin_kernel<<<1024, 256, 0, stream>>>(xh, ctp, csq, ind, flaglist, flagcnt, counts);
  fixup_kernel<<<128, 256, 0, stream>>>(xh, xl, cent, csq, flaglist, flagcnt, ind, counts);
  csnorm_scan_kernel<<<1, 64, 0, stream>>>(cs, counts, icn, offsets, cursor);
  scatter_kernel<<<256, 256, 0, stream>>>(ind, cursor, rowlist);
  sumflush_kernel<<<1024, 256, 0, stream>>>(xh, xl, rowlist, ind, sums);
  newcentT_kernel<<<256, 256, 0, stream>>>(sums, avg, icn, nc);
  gather_kernel<<<512, 256, 0, stream>>>(nc, ind, out);
}

// Round 9
// 332.160 us; speedup vs baseline: 1.1883x; 1.1633x over previous
//
#include <hip/hip_runtime.h>

// x: [64, 256, 32, 32] f32 ; centroids: [256, 1024] ; cluster_size: [1024] ;
// centroids_avg: [256, 1024]
// N = 65536 rows, F = 256, K = 1024.  xf row n = (b*32 + w)*32 + h

#define DECAY 0.99f
#define EPSF 1e-5f
#define DELTA 0.05f

typedef _Float16 f16x8 __attribute__((ext_vector_type(8)));
typedef float f32x4 __attribute__((ext_vector_type(4)));

static __device__ __forceinline__ unsigned short h_bits(_Float16 h) {
  return __builtin_bit_cast(unsigned short, h);
}
static __device__ __forceinline__ float h_val(unsigned short u) {
  return (float)__builtin_bit_cast(_Float16, u);
}

// ---------------- centroid squared norms (fp32 exact) ----------------
__global__ void csq_kernel(const float* __restrict__ cent, float* __restrict__ csq) {
  int k0 = blockIdx.x * 64;
  int t = threadIdx.x;
  int kk = t & 63, cg = t >> 6;
  float s = 0.f;
  for (int c = cg; c < 256; c += 4) {
    float v = cent[(size_t)c * 1024 + k0 + kk];
    s += v * v;
  }
  __shared__ float red[4][64];
  red[cg][kk] = s;
  __syncthreads();
  if (t < 64) csq[k0 + t] = red[0][t] + red[1][t] + red[2][t] + red[3][t];
}

// ---------------- centroids -> packed fp16 B-frag layout ----------------
// ctp element for (k, f): colt=k>>4, lr=k&15, ks=f>>5, lg=(f>>3)&3, e=f&7
// half index = colt*4096 + ks*512 + lr*32 + lg*8 + e
// => a wave's (colt,ks) B-frag load is one contiguous 1 KB segment.
__global__ void centT_kernel(const float* __restrict__ cent, _Float16* __restrict__ ctp) {
  __shared__ float tl[32][33];
  int f0 = (blockIdx.x >> 5) * 32, k0 = (blockIdx.x & 31) * 32;
  int t = threadIdx.x;
#pragma unroll
  for (int i = 0; i < 4; ++i) {
    int fi = (t >> 5) + i * 8, ki = t & 31;
    tl[fi][ki] = cent[(size_t)(f0 + fi) * 1024 + k0 + ki];
  }
  __syncthreads();
#pragma unroll
  for (int i = 0; i < 4; ++i) {
    int ki = (t >> 5) + i * 8, fi = t & 31;
    int k = k0 + ki, f = f0 + fi;
    _Float16 h = (_Float16)tl[fi][ki];
    size_t idx = (size_t)(k >> 4) * 4096 + (size_t)(f >> 5) * 512 +
                 (size_t)(k & 15) * 32 + (size_t)((f >> 3) & 3) * 8 + (f & 7);
    ctp[idx] = h;
  }
}

// ---------------- transpose x -> xh/xl fp16 [65536][256] ----------------
__global__ void transpose_kernel(const float* __restrict__ x, _Float16* __restrict__ xh,
                                 _Float16* __restrict__ xl) {
  __shared__ float tile[64][65];
  int bid = blockIdx.x;
  int pt = bid & 15, ct = (bid >> 4) & 3, b = bid >> 6;
  int c0 = ct * 64, p0 = pt * 64;
  int t = threadIdx.x;
#pragma unroll
  for (int i = 0; i < 16; ++i) {
    int idx = t + i * 256;
    int ci = idx >> 6, pi = idx & 63;
    tile[ci][pi] = x[((size_t)(b * 256 + c0 + ci) << 10) + p0 + pi];
  }
  __syncthreads();
#pragma unroll
  for (int i = 0; i < 8; ++i) {
    int idx = t + i * 256;            // 2048 = 64 p x 32 c-pairs
    int pi = idx >> 5, cp = idx & 31;
    int p = p0 + pi;
    int r = ((p & 31) << 5) | (p >> 5);
    float v0 = tile[cp * 2][pi], v1 = tile[cp * 2 + 1][pi];
    _Float16 h0 = (_Float16)v0, h1 = (_Float16)v1;
    _Float16 l0 = (_Float16)(v0 - (float)h0), l1 = (_Float16)(v1 - (float)h1);
    unsigned int uh = (unsigned int)h_bits(h0) | ((unsigned int)h_bits(h1) << 16);
    unsigned int ul = (unsigned int)h_bits(l0) | ((unsigned int)h_bits(l1) << 16);
    size_t base = ((size_t)((b << 10) + r)) * 128 + ct * 32 + cp;
    ((unsigned int*)xh)[base] = uh;
    ((unsigned int*)xl)[base] = ul;
  }
}

// ---------------- MFMA distance + argmin + 2nd-best margin ----------------
// dist(n,k) = csq[k] - 2*xh.ch  (1 mfma 16x16x32 f16 per tile-combo; validated R8)
// dropped terms error std ~7e-3 << DELTA=0.05; gap<DELTA rows -> exact fixup.
// block: 32 rows x 1024 cols, 4 waves (R6 register shape: no spill at VGPR~52-120).
// Ah in LDS XOR-swizzled; B register double-buffered, inline static rotation.
__global__ __launch_bounds__(256, 4) void mfma_argmin_kernel(
    const _Float16* __restrict__ xh, const _Float16* __restrict__ ctp,
    const float* __restrict__ csq, int* __restrict__ ind,
    int* __restrict__ flaglist, unsigned int* __restrict__ flagcnt,
    unsigned int* __restrict__ counts) {
  __shared__ _Float16 Ah[32 * 256];  // 512 B/row, swizzled
  __shared__ float csql[1024];
  __shared__ float red1[4][32], red2[4][32];
  __shared__ int redk[4][32];
  const int t = threadIdx.x;
  const int lane = t & 63, w = t >> 6;
  const int lr = lane & 15, lg = lane >> 4;
  const int n0 = blockIdx.x * 32;

#pragma unroll
  for (int i = 0; i < 4; ++i) csql[t + i * 256] = csq[t + i * 256];
#pragma unroll
  for (int i = 0; i < 4; ++i) {
    int idx = t + i * 256;            // 1024 = 32 rows x 32 16B-chunks
    int row = idx >> 5, c16 = (idx & 31) * 16;
    int sw = c16 ^ ((row & 7) << 4);
    *(f16x8*)((char*)Ah + row * 512 + sw) =
        *(const f16x8*)((const char*)xh + (size_t)(n0 + row) * 512 + c16);
  }
  __syncthreads();

  float b1[2][4], b2v[2][4];
  int bk[2][4];
#pragma unroll
  for (int rt = 0; rt < 2; ++rt)
#pragma unroll
    for (int rg = 0; rg < 4; ++rg) { b1[rt][rg] = 3.4e38f; b2v[rt][rg] = 3.4e38f; bk[rt][rg] = 0; }

  const int swz = (lr & 7) << 4;
  const int boff = (lr * 4 + lg) * 16;  // byte offset of this lane's frag in a 1KB chunk
#pragma unroll 1
  for (int ch = 0; ch < 4; ++ch) {
    const int ccb = w * 256 + ch * 64;
    const size_t cbase = (size_t)(ccb >> 4) * 8192 + boff;  // 4 col-tiles of 16, 8KB apart
    f32x4 acc[4][2];                  // [ct][rt]
#pragma unroll
    for (int ct = 0; ct < 4; ++ct)
#pragma unroll
      for (int rt = 0; rt < 2; ++rt) acc[ct][rt] = (f32x4){0.f, 0.f, 0.f, 0.f};

    f16x8 pb0[4], pb1[4], ah[2];
    // prologue: B for ks=0
#pragma unroll
    for (int ct = 0; ct < 4; ++ct)
      pb0[ct] = *(const f16x8*)((const char*)ctp + cbase + (size_t)ct * 8192);
#pragma unroll
    for (int ks2 = 0; ks2 < 4; ++ks2) {
      const int ksA = ks2 * 2, ksB = ks2 * 2 + 1;
      // prefetch B for ksB (hides under ksA's MFMA)
#pragma unroll
      for (int ct = 0; ct < 4; ++ct)
        pb1[ct] = *(const f16x8*)((const char*)ctp + cbase + (size_t)ct * 8192 + ksB * 1024);
#pragma unroll
      for (int rt = 0; rt < 2; ++rt)
        ah[rt] = *(const f16x8*)((const char*)Ah + (rt * 16 + lr) * 512 + ((ksA * 64 + lg * 16) ^ swz));
#pragma unroll
      for (int ct = 0; ct < 4; ++ct)
#pragma unroll
        for (int rt = 0; rt < 2; ++rt)
          acc[ct][rt] = __builtin_amdgcn_mfma_f32_16x16x32_f16(ah[rt], pb0[ct], acc[ct][rt], 0, 0, 0);
      if (ks2 < 3) {  // static under full unroll: prefetch B for ksA+2
#pragma unroll
        for (int ct = 0; ct < 4; ++ct)
          pb0[ct] = *(const f16x8*)((const char*)ctp + cbase + (size_t)ct * 8192 + (ksA + 2) * 1024);
      }
#pragma unroll
      for (int rt = 0; rt < 2; ++rt)
        ah[rt] = *(const f16x8*)((const char*)Ah + (rt * 16 + lr) * 512 + ((ksB * 64 + lg * 16) ^ swz));
#pragma unroll
      for (int ct = 0; ct < 4; ++ct)
#pragma unroll
        for (int rt = 0; rt < 2; ++rt)
          acc[ct][rt] = __builtin_amdgcn_mfma_f32_16x16x32_f16(ah[rt], pb1[ct], acc[ct][rt], 0, 0, 0);
    }
    // fold into running best / 2nd-best (cols ascend over time -> first-min tiebreak)
#pragma unroll
    for (int ct = 0; ct < 4; ++ct) {
      const int col = ccb + ct * 16 + lr;
      const float cq = csql[col];
#pragma unroll
      for (int rt = 0; rt < 2; ++rt)
#pragma unroll
        for (int rg = 0; rg < 4; ++rg) {
          float d = cq - 2.f * acc[ct][rt][rg];
          if (d < b1[rt][rg]) {
            b2v[rt][rg] = b1[rt][rg];
            b1[rt][rg] = d;
            bk[rt][rg] = col;
          } else if (d < b2v[rt][rg]) {
            b2v[rt][rg] = d;
          }
        }
    }
  }

  // reduce over the 16 k-lanes of each group
#pragma unroll
  for (int rt = 0; rt < 2; ++rt)
#pragma unroll
    for (int rg = 0; rg < 4; ++rg) {
      float v1 = b1[rt][rg], v2 = b2v[rt][rg];
      int kk = bk[rt][rg];
#pragma unroll
      for (int off = 8; off >= 1; off >>= 1) {
        float o1 = __shfl_xor(v1, off);
        int ok = __shfl_xor(kk, off);
        float o2 = __shfl_xor(v2, off);
        float nb2 = fminf(fmaxf(v1, o1), fminf(v2, o2));
        if (o1 < v1 || (o1 == v1 && ok < kk)) { v1 = o1; kk = ok; }
        v2 = nb2;
      }
      if (lr == 0) {
        int row = rt * 16 + lg * 4 + rg;
        red1[w][row] = v1;
        redk[w][row] = kk;
        red2[w][row] = v2;
      }
    }
  __syncthreads();
  if (t < 32) {
    float v1 = red1[0][t], v2 = red2[0][t];
    int kk = redk[0][t];
#pragma unroll
    for (int wi = 1; wi < 4; ++wi) {
      float o1 = red1[wi][t], o2 = red2[wi][t];
      int ok = redk[wi][t];
      float nb2 = fminf(fmaxf(v1, o1), fminf(v2, o2));
      if (o1 < v1 || (o1 == v1 && ok < kk)) { v1 = o1; kk = ok; }
      v2 = nb2;
    }
    ind[n0 + t] = kk;
    atomicAdd(&counts[kk], 1u);
    if (v2 - v1 < DELTA) {
      unsigned int p = atomicAdd(flagcnt, 1u);
      flaglist[p] = n0 + t;
    }
  }
}

// ---------------- exact fp32 re-argmin for low-margin rows ----------------
__global__ __launch_bounds__(256) void fixup_kernel(
    const _Float16* __restrict__ xh, const _Float16* __restrict__ xl,
    const float* __restrict__ cent, const float* __restrict__ csq,
    const int* __restrict__ flaglist, const unsigned int* __restrict__ flagcnt,
    int* __restrict__ ind, unsigned int* __restrict__ counts) {
  const int t = threadIdx.x;
  const int nf = (int)*flagcnt;
  __shared__ float xrow[256];
  __shared__ float rv[256];
  __shared__ int rk[256];
  for (int ii = blockIdx.x; ii < nf; ii += gridDim.x) {
    __syncthreads();
    int row = flaglist[ii];
    xrow[t] = (float)xh[(size_t)row * 256 + t] + (float)xl[(size_t)row * 256 + t];
    __syncthreads();
    float a0 = 0.f, a1 = 0.f, a2 = 0.f, a3 = 0.f;
#pragma unroll 8
    for (int f = 0; f < 256; ++f) {
      float xs = xrow[f];
      const float* cr = cent + (size_t)f * 1024 + t;
      a0 += xs * cr[0];
      a1 += xs * cr[256];
      a2 += xs * cr[512];
      a3 += xs * cr[768];
    }
    float bd = csq[t] - 2.f * a0;
    int bkk = t;
    float d1 = csq[t + 256] - 2.f * a1;
    if (d1 < bd) { bd = d1; bkk = t + 256; }
    float d2 = csq[t + 512] - 2.f * a2;
    if (d2 < bd) { bd = d2; bkk = t + 512; }
    float d3 = csq[t + 768] - 2.f * a3;
    if (d3 < bd) { bd = d3; bkk = t + 768; }
    rv[t] = bd;
    rk[t] = bkk;
    __syncthreads();
    for (int off = 128; off >= 1; off >>= 1) {
      if (t < off) {
        float ov = rv[t + off];
        int ok = rk[t + off];
        if (ov < rv[t] || (ov == rv[t] && ok < rk[t])) { rv[t] = ov; rk[t] = ok; }
      }
      __syncthreads();
    }
    if (t == 0) {
      int newk = rk[0];
      int oldk = ind[row];
      if (newk != oldk) {
        ind[row] = newk;
        atomicAdd(&counts[oldk], 0xFFFFFFFFu);  // -1
        atomicAdd(&counts[newk], 1u);
      }
    }
  }
}

// ---------------- single-wave: cluster-size EMA/Laplace norm + exclusive scan ----
__global__ __launch_bounds__(64) void csnorm_scan_kernel(
    const float* __restrict__ cs, const unsigned int* __restrict__ counts,
    float* __restrict__ icn, unsigned int* __restrict__ offsets,
    unsigned int* __restrict__ cursor) {
  const int t = threadIdx.x;  // 0..63, each owns 16 clusters
  unsigned int cl[16];
  float csl[16];
  unsigned int s = 0;
  float css = 0.f;
#pragma unroll
  for (int j = 0; j < 16; ++j) {
    cl[j] = counts[t * 16 + j];
    s += cl[j];
    csl[j] = cs[t * 16 + j];
    css += csl[j];
  }
  unsigned int incl = s;
#pragma unroll
  for (int off = 1; off < 64; off <<= 1) {
    unsigned int v = __shfl_up(incl, off);
    if (t >= off) incl += v;
  }
  unsigned int run = incl - s;  // exclusive prefix
  float tot = css;
#pragma unroll
  for (int off = 32; off >= 1; off >>= 1) tot += __shfl_xor(tot, off);
  const float n = DECAY * tot + (1.f - DECAY) * 65536.f;  // sum of new_cs (counts sum = N)
#pragma unroll
  for (int j = 0; j < 16; ++j) {
    int k = t * 16 + j;
    offsets[k] = run;
    cursor[k] = run;
    float ncs = DECAY * csl[j] + (1.f - DECAY) * (float)cl[j];
    float csn = (ncs + EPSF) / (n + 1024.f * EPSF) * n;
    icn[k] = 1.f / csn;
    run += cl[j];
  }
  if (t == 63) offsets[1024] = run;
}

// ---------------- scatter row ids into cluster-ordered list ----------------
__global__ void scatter_kernel(const int* __restrict__ ind, unsigned int* __restrict__ cursor,
                               int* __restrict__ rowlist) {
  int n = blockIdx.x * 256 + threadIdx.x;
  int k = ind[n];
  unsigned int pos = atomicAdd(&cursor[k], 1u);
  rowlist[pos] = n;
}

// ---------------- balanced segment-sum: position-partitioned + boundary flush ----
// xh-only sum: dropped xl contribution error ~1e-4 relative on output (<<2.88 thr).
__global__ __launch_bounds__(256) void sumflush_kernel(
    const _Float16* __restrict__ xh, const int* __restrict__ rowlist,
    const int* __restrict__ ind, float* __restrict__ sums) {
  __shared__ int rl[64];
  __shared__ int kl[64];
  const int t = threadIdx.x;
  const int sub = t >> 6, lane = t & 63;
  const int p0 = blockIdx.x * 64;
  if (t < 64) {
    int r = rowlist[p0 + t];
    rl[t] = r;
    kl[t] = ind[r];
  }
  __syncthreads();
  float a0 = 0.f, a1 = 0.f, a2 = 0.f, a3 = 0.f;
  int curk = kl[sub * 16];
#pragma unroll
  for (int i = 0; i < 16; ++i) {
    int p = sub * 16 + i;
    int k = kl[p];
    if (k != curk) {  // wave-uniform branch (k uniform across the wave)
      float* dst = &sums[(size_t)curk * 256 + lane * 4];
      atomicAdd(&dst[0], a0);
      atomicAdd(&dst[1], a1);
      atomicAdd(&dst[2], a2);
      atomicAdd(&dst[3], a3);
      a0 = a1 = a2 = a3 = 0.f;
      curk = k;
    }
    int r = rl[p];
    uint2 vh = *(const uint2*)&((const unsigned int*)xh)[(size_t)r * 128 + lane * 2];
    a0 += h_val((unsigned short)(vh.x & 0xFFFF));
    a1 += h_val((unsigned short)(vh.x >> 16));
    a2 += h_val((unsigned short)(vh.y & 0xFFFF));
    a3 += h_val((unsigned short)(vh.y >> 16));
  }
  float* dst = &sums[(size_t)curk * 256 + lane * 4];
  atomicAdd(&dst[0], a0);
  atomicAdd(&dst[1], a1);
  atomicAdd(&dst[2], a2);
  atomicAdd(&dst[3], a3);
}

// ---------------- centroid EMA + scale, [k][f] -> [f][k] transpose ----------------
__global__ __launch_bounds__(256) void newcentT_kernel(
    const float* __restrict__ sums, const float* __restrict__ avg,
    const float* __restrict__ icn, float* __restrict__ nc) {
  __shared__ float tl[32][33];
  const int t = threadIdx.x;
  const int k0 = (blockIdx.x & 31) * 32, f0 = (blockIdx.x >> 5) * 32;
#pragma unroll
  for (int i = 0; i < 4; ++i) {
    int ki = (t >> 5) + i * 8, fi = t & 31;
    tl[ki][fi] = sums[(size_t)(k0 + ki) * 256 + f0 + fi];
  }
  __syncthreads();
#pragma unroll
  for (int i = 0; i < 4; ++i) {
    int fi = (t >> 5) + i * 8, ki = t & 31;
    size_t idx = (size_t)(f0 + fi) * 1024 + k0 + ki;
    nc[idx] = (DECAY * avg[idx] + (1.f - DECAY) * tl[ki][fi]) * icn[k0 + ki];
  }
}

// ---------------- gather output: out[b][c][h][w] = nc[c][ind[n(b,w,h)]] ----------------
__global__ void gather_kernel(const float* __restrict__ nc, const int* __restrict__ ind,
                              float* __restrict__ out) {
  __shared__ int ip[1024];
  int b = blockIdx.x >> 3;
  int cg = (blockIdx.x & 7) * 32;
  int t = threadIdx.x;
#pragma unroll
  for (int j = 0; j < 4; ++j) {
    int p = t + j * 256;                 // p = h*32 + w
    int r = ((p & 31) << 5) | (p >> 5);  // r = w*32 + h
    ip[p] = ind[(b << 10) + r];
  }
  __syncthreads();
  for (int c = cg; c < cg + 32; ++c) {
    const float* row = nc + (size_t)c * 1024;
#pragma unroll
    for (int j = 0; j < 4; ++j) {
      int p = t + j * 256;
      out[((size_t)(b * 256 + c) << 10) + p] = row[ip[p]];
    }
  }
}

extern "C" void kernel_launch(void* const* d_in, const int* in_sizes, int n_in,
                              void* d_out, int out_size, void* d_ws, size_t ws_size,
                              hipStream_t stream) {
  const float* x = (const float*)d_in[0];
  const float* cent = (const float*)d_in[1];
  const float* cs = (const float*)d_in[2];
  const float* avg = (const float*)d_in[3];
  float* out = (float*)d_out;

  char* ws = (char*)d_ws;
  _Float16* xh = (_Float16*)ws;                              // 32 MB
  _Float16* xl = (_Float16*)(ws + 33554432);                 // 32 MB
  _Float16* ctp = (_Float16*)(ws + 67108864);                // 512 KB packed B
  float* nc = (float*)(ws + 67108864);                       // 1 MB (aliases ctp; disjoint lifetime)
  unsigned int* counts = (unsigned int*)(ws + 68157440);     // 4 KB
  unsigned int* flagcnt = (unsigned int*)(ws + 68161536);    // 4 KB
  float* csq = (float*)(ws + 68165632);                      // 4 KB
  float* icn = (float*)(ws + 68169728);                      // 4 KB
  unsigned int* offsets = (unsigned int*)(ws + 68173824);    // 8 KB (1025 used)
  unsigned int* cursor = (unsigned int*)(ws + 68182016);     // 4 KB
  int* ind = (int*)(ws + 68186112);                          // 256 KB
  int* flaglist = (int*)(ws + 68448256);                     // 256 KB (aliases rowlist; disjoint lifetime)
  int* rowlist = (int*)(ws + 68448256);
  float* sums = (float*)(ws + 68710400);                     // 1 MB [k][f]

  hipMemsetAsync(counts, 0, 8192, stream);   // counts + flagcnt
  hipMemsetAsync(sums, 0, 1048576, stream);  // sums

  csq_kernel<<<16, 256, 0, stream>>>(cent, csq);
  centT_kernel<<<256, 256, 0, stream>>>(cent, ctp);
  transpose_kernel<<<4096, 256, 0, stream>>>(x, xh, xl);
  mfma_argmin_kernel<<<2048, 256, 0, stream>>>(xh, ctp, csq, ind, flaglist, flagcnt, counts);
  fixup_kernel<<<128, 256, 0, stream>>>(xh, xl, cent, csq, flaglist, flagcnt, ind, counts);
  csnorm_scan_kernel<<<1, 64, 0, stream>>>(cs, counts, icn, offsets, cursor);
  scatter_kernel<<<256, 256, 0, stream>>>(ind, cursor, rowlist);
  sumflush_kernel<<<1024, 256, 0, stream>>>(xh, rowlist, ind, sums);
  newcentT_kernel<<<256, 256, 0, stream>>>(sums, avg, icn, nc);
  gather_kernel<<<512, 256, 0, stream>>>(nc, ind, out);
}

// Round 10
// 290.367 us; speedup vs baseline: 1.3594x; 1.1439x over previous
//
#include <hip/hip_runtime.h>

// x: [64, 256, 32, 32] f32 ; centroids: [256, 1024] ; cluster_size: [1024] ;
// centroids_avg: [256, 1024]
// N = 65536 rows, F = 256, K = 1024.  xf row n = (b*32 + w)*32 + h

#define DECAY 0.99f
#define EPSF 1e-5f
#define DELTA 0.05f

typedef _Float16 f16x8 __attribute__((ext_vector_type(8)));
typedef float f32x4 __attribute__((ext_vector_type(4)));

static __device__ __forceinline__ unsigned short h_bits(_Float16 h) {
  return __builtin_bit_cast(unsigned short, h);
}
static __device__ __forceinline__ float h_val(unsigned short u) {
  return (float)__builtin_bit_cast(_Float16, u);
}

// ---------------- centroid squared norms (fp32 exact) ----------------
__global__ void csq_kernel(const float* __restrict__ cent, float* __restrict__ csq) {
  int k0 = blockIdx.x * 64;
  int t = threadIdx.x;
  int kk = t & 63, cg = t >> 6;
  float s = 0.f;
  for (int c = cg; c < 256; c += 4) {
    float v = cent[(size_t)c * 1024 + k0 + kk];
    s += v * v;
  }
  __shared__ float red[4][64];
  red[cg][kk] = s;
  __syncthreads();
  if (t < 64) csq[k0 + t] = red[0][t] + red[1][t] + red[2][t] + red[3][t];
}

// ---------------- centroids -> packed fp16 B-frag layout ----------------
// ctp element for (k, f): colt=k>>4, lr=k&15, ks=f>>5, lg=(f>>3)&3, e=f&7
// half index = colt*4096 + ks*512 + lr*32 + lg*8 + e
// => a wave's (colt,ks) B-frag load is one contiguous 1 KB segment.
__global__ void centT_kernel(const float* __restrict__ cent, _Float16* __restrict__ ctp) {
  __shared__ float tl[32][33];
  int f0 = (blockIdx.x >> 5) * 32, k0 = (blockIdx.x & 31) * 32;
  int t = threadIdx.x;
#pragma unroll
  for (int i = 0; i < 4; ++i) {
    int fi = (t >> 5) + i * 8, ki = t & 31;
    tl[fi][ki] = cent[(size_t)(f0 + fi) * 1024 + k0 + ki];
  }
  __syncthreads();
#pragma unroll
  for (int i = 0; i < 4; ++i) {
    int ki = (t >> 5) + i * 8, fi = t & 31;
    int k = k0 + ki, f = f0 + fi;
    _Float16 h = (_Float16)tl[fi][ki];
    size_t idx = (size_t)(k >> 4) * 4096 + (size_t)(f >> 5) * 512 +
                 (size_t)(k & 15) * 32 + (size_t)((f >> 3) & 3) * 8 + (f & 7);
    ctp[idx] = h;
  }
}

// ---------------- transpose x -> xh/xl fp16 [65536][256] ----------------
__global__ void transpose_kernel(const float* __restrict__ x, _Float16* __restrict__ xh,
                                 _Float16* __restrict__ xl) {
  __shared__ float tile[64][65];
  int bid = blockIdx.x;
  int pt = bid & 15, ct = (bid >> 4) & 3, b = bid >> 6;
  int c0 = ct * 64, p0 = pt * 64;
  int t = threadIdx.x;
#pragma unroll
  for (int i = 0; i < 16; ++i) {
    int idx = t + i * 256;
    int ci = idx >> 6, pi = idx & 63;
    tile[ci][pi] = x[((size_t)(b * 256 + c0 + ci) << 10) + p0 + pi];
  }
  __syncthreads();
#pragma unroll
  for (int i = 0; i < 8; ++i) {
    int idx = t + i * 256;            // 2048 = 64 p x 32 c-pairs
    int pi = idx >> 5, cp = idx & 31;
    int p = p0 + pi;
    int r = ((p & 31) << 5) | (p >> 5);
    float v0 = tile[cp * 2][pi], v1 = tile[cp * 2 + 1][pi];
    _Float16 h0 = (_Float16)v0, h1 = (_Float16)v1;
    _Float16 l0 = (_Float16)(v0 - (float)h0), l1 = (_Float16)(v1 - (float)h1);
    unsigned int uh = (unsigned int)h_bits(h0) | ((unsigned int)h_bits(h1) << 16);
    unsigned int ul = (unsigned int)h_bits(l0) | ((unsigned int)h_bits(l1) << 16);
    size_t base = ((size_t)((b << 10) + r)) * 128 + ct * 32 + cp;
    ((unsigned int*)xh)[base] = uh;
    ((unsigned int*)xl)[base] = ul;
  }
}

// ---------------- MFMA distance + argmin + 2nd-best margin ----------------
// dist(n,k) = csq[k] - 2*xh.ch  (1 mfma 16x16x32 f16 per tile-combo; validated R8/R9)
// dropped terms error std ~7e-3 << DELTA=0.05; gap<DELTA rows -> exact fixup.
// block: 64 rows x 1024 cols, 4 waves, rt=4 (16 MFMA per 4 B-loads).
// R6 loop style: loads issued inline per iteration, NO cross-iteration register
// buffers (every explicit prefetch variant spilled: R5/R7/R8/R9).
__global__ __launch_bounds__(256, 3) void mfma_argmin_kernel(
    const _Float16* __restrict__ xh, const _Float16* __restrict__ ctp,
    const float* __restrict__ csq, int* __restrict__ ind,
    int* __restrict__ flaglist, unsigned int* __restrict__ flagcnt,
    unsigned int* __restrict__ counts) {
  __shared__ _Float16 Ah[64 * 256];  // 512 B/row, XOR-swizzled
  __shared__ float csql[1024];
  __shared__ float red1[4][64], red2[4][64];
  __shared__ int redk[4][64];
  const int t = threadIdx.x;
  const int lane = t & 63, w = t >> 6;
  const int lr = lane & 15, lg = lane >> 4;
  const int n0 = blockIdx.x * 64;

#pragma unroll
  for (int i = 0; i < 4; ++i) csql[t + i * 256] = csq[t + i * 256];
#pragma unroll
  for (int i = 0; i < 8; ++i) {
    int idx = t + i * 256;            // 2048 = 64 rows x 32 16B-chunks
    int row = idx >> 5, c16 = (idx & 31) * 16;
    int sw = c16 ^ ((row & 7) << 4);
    *(f16x8*)((char*)Ah + row * 512 + sw) =
        *(const f16x8*)((const char*)xh + (size_t)(n0 + row) * 512 + c16);
  }
  __syncthreads();

  float b1[4][4], b2v[4][4];
  int bk[4][4];
#pragma unroll
  for (int rt = 0; rt < 4; ++rt)
#pragma unroll
    for (int rg = 0; rg < 4; ++rg) { b1[rt][rg] = 3.4e38f; b2v[rt][rg] = 3.4e38f; bk[rt][rg] = 0; }

  const int swz = (lr & 7) << 4;
  const int boff = (lr * 4 + lg) * 16;  // byte offset of this lane's frag in a 1KB chunk
#pragma unroll 1
  for (int ch = 0; ch < 4; ++ch) {
    const int ccb = w * 256 + ch * 64;
    const size_t cbase = (size_t)(ccb >> 4) * 8192 + boff;  // 4 col-tiles of 16, 8KB apart
    f32x4 acc[4][4];                  // [ct][rt]
#pragma unroll
    for (int ct = 0; ct < 4; ++ct)
#pragma unroll
      for (int rt = 0; rt < 4; ++rt) acc[ct][rt] = (f32x4){0.f, 0.f, 0.f, 0.f};

#pragma unroll 1
    for (int ks = 0; ks < 8; ++ks) {
      f16x8 bh[4], ah[4];
#pragma unroll
      for (int ct = 0; ct < 4; ++ct)
        bh[ct] = *(const f16x8*)((const char*)ctp + cbase + (size_t)ct * 8192 + ks * 1024);
#pragma unroll
      for (int rt = 0; rt < 4; ++rt)
        ah[rt] = *(const f16x8*)((const char*)Ah + (rt * 16 + lr) * 512 + ((ks * 64 + lg * 16) ^ swz));
#pragma unroll
      for (int ct = 0; ct < 4; ++ct)
#pragma unroll
        for (int rt = 0; rt < 4; ++rt)
          acc[ct][rt] = __builtin_amdgcn_mfma_f32_16x16x32_f16(ah[rt], bh[ct], acc[ct][rt], 0, 0, 0);
    }
    // fold into running best / 2nd-best (cols ascend over time -> first-min tiebreak)
#pragma unroll
    for (int ct = 0; ct < 4; ++ct) {
      const int col = ccb + ct * 16 + lr;
      const float cq = csql[col];
#pragma unroll
      for (int rt = 0; rt < 4; ++rt)
#pragma unroll
        for (int rg = 0; rg < 4; ++rg) {
          float d = cq - 2.f * acc[ct][rt][rg];
          if (d < b1[rt][rg]) {
            b2v[rt][rg] = b1[rt][rg];
            b1[rt][rg] = d;
            bk[rt][rg] = col;
          } else if (d < b2v[rt][rg]) {
            b2v[rt][rg] = d;
          }
        }
    }
  }

  // reduce over the 16 k-lanes of each group
#pragma unroll
  for (int rt = 0; rt < 4; ++rt)
#pragma unroll
    for (int rg = 0; rg < 4; ++rg) {
      float v1 = b1[rt][rg], v2 = b2v[rt][rg];
      int kk = bk[rt][rg];
#pragma unroll
      for (int off = 8; off >= 1; off >>= 1) {
        float o1 = __shfl_xor(v1, off);
        int ok = __shfl_xor(kk, off);
        float o2 = __shfl_xor(v2, off);
        float nb2 = fminf(fmaxf(v1, o1), fminf(v2, o2));
        if (o1 < v1 || (o1 == v1 && ok < kk)) { v1 = o1; kk = ok; }
        v2 = nb2;
      }
      if (lr == 0) {
        int row = rt * 16 + lg * 4 + rg;
        red1[w][row] = v1;
        redk[w][row] = kk;
        red2[w][row] = v2;
      }
    }
  __syncthreads();
  if (t < 64) {
    float v1 = red1[0][t], v2 = red2[0][t];
    int kk = redk[0][t];
#pragma unroll
    for (int wi = 1; wi < 4; ++wi) {
      float o1 = red1[wi][t], o2 = red2[wi][t];
      int ok = redk[wi][t];
      float nb2 = fminf(fmaxf(v1, o1), fminf(v2, o2));
      if (o1 < v1 || (o1 == v1 && ok < kk)) { v1 = o1; kk = ok; }
      v2 = nb2;
    }
    ind[n0 + t] = kk;
    atomicAdd(&counts[kk], 1u);
    if (v2 - v1 < DELTA) {
      unsigned int p = atomicAdd(flagcnt, 1u);
      flaglist[p] = n0 + t;
    }
  }
}

// ---------------- exact fp32 re-argmin for low-margin rows ----------------
__global__ __launch_bounds__(256) void fixup_kernel(
    const _Float16* __restrict__ xh, const _Float16* __restrict__ xl,
    const float* __restrict__ cent, const float* __restrict__ csq,
    const int* __restrict__ flaglist, const unsigned int* __restrict__ flagcnt,
    int* __restrict__ ind, unsigned int* __restrict__ counts) {
  const int t = threadIdx.x;
  const int nf = (int)*flagcnt;
  __shared__ float xrow[256];
  __shared__ float rv[256];
  __shared__ int rk[256];
  for (int ii = blockIdx.x; ii < nf; ii += gridDim.x) {
    __syncthreads();
    int row = flaglist[ii];
    xrow[t] = (float)xh[(size_t)row * 256 + t] + (float)xl[(size_t)row * 256 + t];
    __syncthreads();
    float a0 = 0.f, a1 = 0.f, a2 = 0.f, a3 = 0.f;
#pragma unroll 8
    for (int f = 0; f < 256; ++f) {
      float xs = xrow[f];
      const float* cr = cent + (size_t)f * 1024 + t;
      a0 += xs * cr[0];
      a1 += xs * cr[256];
      a2 += xs * cr[512];
      a3 += xs * cr[768];
    }
    float bd = csq[t] - 2.f * a0;
    int bkk = t;
    float d1 = csq[t + 256] - 2.f * a1;
    if (d1 < bd) { bd = d1; bkk = t + 256; }
    float d2 = csq[t + 512] - 2.f * a2;
    if (d2 < bd) { bd = d2; bkk = t + 512; }
    float d3 = csq[t + 768] - 2.f * a3;
    if (d3 < bd) { bd = d3; bkk = t + 768; }
    rv[t] = bd;
    rk[t] = bkk;
    __syncthreads();
    for (int off = 128; off >= 1; off >>= 1) {
      if (t < off) {
        float ov = rv[t + off];
        int ok = rk[t + off];
        if (ov < rv[t] || (ov == rv[t] && ok < rk[t])) { rv[t] = ov; rk[t] = ok; }
      }
      __syncthreads();
    }
    if (t == 0) {
      int newk = rk[0];
      int oldk = ind[row];
      if (newk != oldk) {
        ind[row] = newk;
        atomicAdd(&counts[oldk], 0xFFFFFFFFu);  // -1
        atomicAdd(&counts[newk], 1u);
      }
    }
  }
}

// ---------------- single-wave: cluster-size EMA/Laplace norm + exclusive scan ----
__global__ __launch_bounds__(64) void csnorm_scan_kernel(
    const float* __restrict__ cs, const unsigned int* __restrict__ counts,
    float* __restrict__ icn, unsigned int* __restrict__ offsets,
    unsigned int* __restrict__ cursor) {
  const int t = threadIdx.x;  // 0..63, each owns 16 clusters
  unsigned int cl[16];
  float csl[16];
  unsigned int s = 0;
  float css = 0.f;
#pragma unroll
  for (int j = 0; j < 16; ++j) {
    cl[j] = counts[t * 16 + j];
    s += cl[j];
    csl[j] = cs[t * 16 + j];
    css += csl[j];
  }
  unsigned int incl = s;
#pragma unroll
  for (int off = 1; off < 64; off <<= 1) {
    unsigned int v = __shfl_up(incl, off);
    if (t >= off) incl += v;
  }
  unsigned int run = incl - s;  // exclusive prefix
  float tot = css;
#pragma unroll
  for (int off = 32; off >= 1; off >>= 1) tot += __shfl_xor(tot, off);
  const float n = DECAY * tot + (1.f - DECAY) * 65536.f;  // sum of new_cs (counts sum = N)
#pragma unroll
  for (int j = 0; j < 16; ++j) {
    int k = t * 16 + j;
    offsets[k] = run;
    cursor[k] = run;
    float ncs = DECAY * csl[j] + (1.f - DECAY) * (float)cl[j];
    float csn = (ncs + EPSF) / (n + 1024.f * EPSF) * n;
    icn[k] = 1.f / csn;
    run += cl[j];
  }
  if (t == 63) offsets[1024] = run;
}

// ---------------- scatter row ids into cluster-ordered list ----------------
__global__ void scatter_kernel(const int* __restrict__ ind, unsigned int* __restrict__ cursor,
                               int* __restrict__ rowlist) {
  int n = blockIdx.x * 256 + threadIdx.x;
  int k = ind[n];
  unsigned int pos = atomicAdd(&cursor[k], 1u);
  rowlist[pos] = n;
}

// ---------------- balanced segment-sum: position-partitioned + boundary flush ----
// xh-only sum: dropped xl contribution error ~1e-4 relative on output (<<2.88 thr).
__global__ __launch_bounds__(256) void sumflush_kernel(
    const _Float16* __restrict__ xh, const int* __restrict__ rowlist,
    const int* __restrict__ ind, float* __restrict__ sums) {
  __shared__ int rl[64];
  __shared__ int kl[64];
  const int t = threadIdx.x;
  const int sub = t >> 6, lane = t & 63;
  const int p0 = blockIdx.x * 64;
  if (t < 64) {
    int r = rowlist[p0 + t];
    rl[t] = r;
    kl[t] = ind[r];
  }
  __syncthreads();
  float a0 = 0.f, a1 = 0.f, a2 = 0.f, a3 = 0.f;
  int curk = kl[sub * 16];
#pragma unroll
  for (int i = 0; i < 16; ++i) {
    int p = sub * 16 + i;
    int k = kl[p];
    if (k != curk) {  // wave-uniform branch (k uniform across the wave)
      float* dst = &sums[(size_t)curk * 256 + lane * 4];
      atomicAdd(&dst[0], a0);
      atomicAdd(&dst[1], a1);
      atomicAdd(&dst[2], a2);
      atomicAdd(&dst[3], a3);
      a0 = a1 = a2 = a3 = 0.f;
      curk = k;
    }
    int r = rl[p];
    uint2 vh = *(const uint2*)&((const unsigned int*)xh)[(size_t)r * 128 + lane * 2];
    a0 += h_val((unsigned short)(vh.x & 0xFFFF));
    a1 += h_val((unsigned short)(vh.x >> 16));
    a2 += h_val((unsigned short)(vh.y & 0xFFFF));
    a3 += h_val((unsigned short)(vh.y >> 16));
  }
  float* dst = &sums[(size_t)curk * 256 + lane * 4];
  atomicAdd(&dst[0], a0);
  atomicAdd(&dst[1], a1);
  atomicAdd(&dst[2], a2);
  atomicAdd(&dst[3], a3);
}

// ---------------- centroid EMA + scale, [k][f] -> [f][k] transpose ----------------
__global__ __launch_bounds__(256) void newcentT_kernel(
    const float* __restrict__ sums, const float* __restrict__ avg,
    const float* __restrict__ icn, float* __restrict__ nc) {
  __shared__ float tl[32][33];
  const int t = threadIdx.x;
  const int k0 = (blockIdx.x & 31) * 32, f0 = (blockIdx.x >> 5) * 32;
#pragma unroll
  for (int i = 0; i < 4; ++i) {
    int ki = (t >> 5) + i * 8, fi = t & 31;
    tl[ki][fi] = sums[(size_t)(k0 + ki) * 256 + f0 + fi];
  }
  __syncthreads();
#pragma unroll
  for (int i = 0; i < 4; ++i) {
    int fi = (t >> 5) + i * 8, ki = t & 31;
    size_t idx = (size_t)(f0 + fi) * 1024 + k0 + ki;
    nc[idx] = (DECAY * avg[idx] + (1.f - DECAY) * tl[ki][fi]) * icn[k0 + ki];
  }
}

// ---------------- gather output: out[b][c][h][w] = nc[c][ind[n(b,w,h)]] ----------------
__global__ void gather_kernel(const float* __restrict__ nc, const int* __restrict__ ind,
                              float* __restrict__ out) {
  __shared__ int ip[1024];
  int b = blockIdx.x >> 3;
  int cg = (blockIdx.x & 7) * 32;
  int t = threadIdx.x;
#pragma unroll
  for (int j = 0; j < 4; ++j) {
    int p = t + j * 256;                 // p = h*32 + w
    int r = ((p & 31) << 5) | (p >> 5);  // r = w*32 + h
    ip[p] = ind[(b << 10) + r];
  }
  __syncthreads();
  for (int c = cg; c < cg + 32; ++c) {
    const float* row = nc + (size_t)c * 1024;
#pragma unroll
    for (int j = 0; j < 4; ++j) {
      int p = t + j * 256;
      out[((size_t)(b * 256 + c) << 10) + p] = row[ip[p]];
    }
  }
}

extern "C" void kernel_launch(void* const* d_in, const int* in_sizes, int n_in,
                              void* d_out, int out_size, void* d_ws, size_t ws_size,
                              hipStream_t stream) {
  const float* x = (const float*)d_in[0];
  const float* cent = (const float*)d_in[1];
  const float* cs = (const float*)d_in[2];
  const float* avg = (const float*)d_in[3];
  float* out = (float*)d_out;

  char* ws = (char*)d_ws;
  _Float16* xh = (_Float16*)ws;                              // 32 MB
  _Float16* xl = (_Float16*)(ws + 33554432);                 // 32 MB
  _Float16* ctp = (_Float16*)(ws + 67108864);                // 512 KB packed B
  float* nc = (float*)(ws + 67108864);                       // 1 MB (aliases ctp; disjoint lifetime)
  unsigned int* counts = (unsigned int*)(ws + 68157440);     // 4 KB
  unsigned int* flagcnt = (unsigned int*)(ws + 68161536);    // 4 KB
  float* csq = (float*)(ws + 68165632);                      // 4 KB
  float* icn = (float*)(ws + 68169728);                      // 4 KB
  unsigned int* offsets = (unsigned int*)(ws + 68173824);    // 8 KB (1025 used)
  unsigned int* cursor = (unsigned int*)(ws + 68182016);     // 4 KB
  int* ind = (int*)(ws + 68186112);                          // 256 KB
  int* flaglist = (int*)(ws + 68448256);                     // 256 KB (aliases rowlist; disjoint lifetime)
  int* rowlist = (int*)(ws + 68448256);
  float* sums = (float*)(ws + 68710400);                     // 1 MB [k][f]

  hipMemsetAsync(counts, 0, 8192, stream);   // counts + flagcnt
  hipMemsetAsync(sums, 0, 1048576, stream);  // sums

  csq_kernel<<<16, 256, 0, stream>>>(cent, csq);
  centT_kernel<<<256, 256, 0, stream>>>(cent, ctp);
  transpose_kernel<<<4096, 256, 0, stream>>>(x, xh, xl);
  mfma_argmin_kernel<<<1024, 256, 0, stream>>>(xh, ctp, csq, ind, flaglist, flagcnt, counts);
  fixup_kernel<<<128, 256, 0, stream>>>(xh, xl, cent, csq, flaglist, flagcnt, ind, counts);
  csnorm_scan_kernel<<<1, 64, 0, stream>>>(cs, counts, icn, offsets, cursor);
  scatter_kernel<<<256, 256, 0, stream>>>(ind, cursor, rowlist);
  sumflush_kernel<<<1024, 256, 0, stream>>>(xh, rowlist, ind, sums);
  newcentT_kernel<<<256, 256, 0, stream>>>(sums, avg, icn, nc);
  gather_kernel<<<512, 256, 0, stream>>>(nc, ind, out);
}

// Round 11
// 277.876 us; speedup vs baseline: 1.4205x; 1.0450x over previous
//
#include <hip/hip_runtime.h>

// x: [64, 256, 32, 32] f32 ; centroids: [256, 1024] ; cluster_size: [1024] ;
// centroids_avg: [256, 1024]
// N = 65536 rows, F = 256, K = 1024.  xf row n = (b*32 + w)*32 + h

#define DECAY 0.99f
#define EPSF 1e-5f
#define DELTA 0.05f

typedef _Float16 f16x8 __attribute__((ext_vector_type(8)));
typedef float f32x4 __attribute__((ext_vector_type(4)));

static __device__ __forceinline__ unsigned short h_bits(_Float16 h) {
  return __builtin_bit_cast(unsigned short, h);
}
static __device__ __forceinline__ float h_val(unsigned short u) {
  return (float)__builtin_bit_cast(_Float16, u);
}

// ---------------- centroid squared norms (fp32 exact) ----------------
__global__ void csq_kernel(const float* __restrict__ cent, float* __restrict__ csq) {
  int k0 = blockIdx.x * 64;
  int t = threadIdx.x;
  int kk = t & 63, cg = t >> 6;
  float s = 0.f;
  for (int c = cg; c < 256; c += 4) {
    float v = cent[(size_t)c * 1024 + k0 + kk];
    s += v * v;
  }
  __shared__ float red[4][64];
  red[cg][kk] = s;
  __syncthreads();
  if (t < 64) csq[k0 + t] = red[0][t] + red[1][t] + red[2][t] + red[3][t];
}

// ---------------- centroids -> packed fp16 B-frag layout ----------------
// ctp element for (k, f): colt=k>>4, lr=k&15, ks=f>>5, lg=(f>>3)&3, e=f&7
// half index = colt*4096 + ks*512 + lr*32 + lg*8 + e
// => a wave's (colt,ks) B-frag chunk is one contiguous 1 KB segment (DMA-able).
__global__ void centT_kernel(const float* __restrict__ cent, _Float16* __restrict__ ctp) {
  __shared__ float tl[32][33];
  int f0 = (blockIdx.x >> 5) * 32, k0 = (blockIdx.x & 31) * 32;
  int t = threadIdx.x;
#pragma unroll
  for (int i = 0; i < 4; ++i) {
    int fi = (t >> 5) + i * 8, ki = t & 31;
    tl[fi][ki] = cent[(size_t)(f0 + fi) * 1024 + k0 + ki];
  }
  __syncthreads();
#pragma unroll
  for (int i = 0; i < 4; ++i) {
    int ki = (t >> 5) + i * 8, fi = t & 31;
    int k = k0 + ki, f = f0 + fi;
    _Float16 h = (_Float16)tl[fi][ki];
    size_t idx = (size_t)(k >> 4) * 4096 + (size_t)(f >> 5) * 512 +
                 (size_t)(k & 15) * 32 + (size_t)((f >> 3) & 3) * 8 + (f & 7);
    ctp[idx] = h;
  }
}

// ---------------- transpose x -> xh/xl fp16 [65536][256] ----------------
__global__ void transpose_kernel(const float* __restrict__ x, _Float16* __restrict__ xh,
                                 _Float16* __restrict__ xl) {
  __shared__ float tile[64][65];
  int bid = blockIdx.x;
  int pt = bid & 15, ct = (bid >> 4) & 3, b = bid >> 6;
  int c0 = ct * 64, p0 = pt * 64;
  int t = threadIdx.x;
#pragma unroll
  for (int i = 0; i < 16; ++i) {
    int idx = t + i * 256;
    int ci = idx >> 6, pi = idx & 63;
    tile[ci][pi] = x[((size_t)(b * 256 + c0 + ci) << 10) + p0 + pi];
  }
  __syncthreads();
#pragma unroll
  for (int i = 0; i < 8; ++i) {
    int idx = t + i * 256;            // 2048 = 64 p x 32 c-pairs
    int pi = idx >> 5, cp = idx & 31;
    int p = p0 + pi;
    int r = ((p & 31) << 5) | (p >> 5);
    float v0 = tile[cp * 2][pi], v1 = tile[cp * 2 + 1][pi];
    _Float16 h0 = (_Float16)v0, h1 = (_Float16)v1;
    _Float16 l0 = (_Float16)(v0 - (float)h0), l1 = (_Float16)(v1 - (float)h1);
    unsigned int uh = (unsigned int)h_bits(h0) | ((unsigned int)h_bits(h1) << 16);
    unsigned int ul = (unsigned int)h_bits(l0) | ((unsigned int)h_bits(l1) << 16);
    size_t base = ((size_t)((b << 10) + r)) * 128 + ct * 32 + cp;
    ((unsigned int*)xh)[base] = uh;
    ((unsigned int*)xl)[base] = ul;
  }
}

// ---------------- MFMA distance + argmin + 2nd-best margin ----------------
// dist(n,k) = csq[k] - 2*xh.ch  (1-term; validated R8-R10; gap<DELTA -> exact fixup)
// Convoy-breaker (R10 diagnosis): wave-private LDS double-buffer for B filled by
// global_load_lds DMA with counted vmcnt(4) (never 0 mid-loop). No barriers in the
// K-loop (per-wave buffers), no cross-iteration registers (no spill path).
__global__ __launch_bounds__(256, 2) void mfma_argmin_kernel(
    const _Float16* __restrict__ xh, const _Float16* __restrict__ ctp,
    const float* __restrict__ csq, int* __restrict__ ind,
    int* __restrict__ flaglist, unsigned int* __restrict__ flagcnt,
    unsigned int* __restrict__ counts) {
  __shared__ _Float16 Ah[64 * 256];         // 32 KB, 512 B/row, XOR-swizzled
  __shared__ _Float16 Bst[4 * 2 * 4 * 512]; // 32 KB: [wave][parity][ct][512 halfs]
  __shared__ float csql[1024];
  __shared__ float red1[4][64], red2[4][64];
  __shared__ int redk[4][64];
  const int t = threadIdx.x;
  const int lane = t & 63, w = t >> 6;
  const int lr = lane & 15, lg = lane >> 4;
  const int n0 = blockIdx.x * 64;

#pragma unroll
  for (int i = 0; i < 4; ++i) csql[t + i * 256] = csq[t + i * 256];
#pragma unroll
  for (int i = 0; i < 8; ++i) {
    int idx = t + i * 256;            // 2048 = 64 rows x 32 16B-chunks
    int row = idx >> 5, c16 = (idx & 31) * 16;
    int sw = c16 ^ ((row & 7) << 4);
    *(f16x8*)((char*)Ah + row * 512 + sw) =
        *(const f16x8*)((const char*)xh + (size_t)(n0 + row) * 512 + c16);
  }
  __syncthreads();   // drains vmcnt: staging loads retired before DMA counting starts

  float b1[4][4], b2v[4][4];
  int bk[4][4];
#pragma unroll
  for (int rt = 0; rt < 4; ++rt)
#pragma unroll
    for (int rg = 0; rg < 4; ++rg) { b1[rt][rg] = 3.4e38f; b2v[rt][rg] = 3.4e38f; bk[rt][rg] = 0; }

  const int swz = (lr & 7) << 4;
  const int boffh = (lr * 4 + lg) * 8;      // this lane's frag (halfs) within a 1KB chunk
  const size_t lgo = (size_t)lane * 16;     // DMA: lane's byte offset within a chunk
  _Float16* bw = &Bst[w * 4096];            // wave-private 8 KB region

// DMA one ks-step's 4 chunks (4 KB) into parity P (fire-and-forget, 4 vmcnt slots)
#define DMA4(CHB, KS, P)                                                              \
  do {                                                                                \
    const char* g_ = (const char*)ctp + (CHB) + (size_t)(KS) * 1024 + lgo;            \
    _Float16* l_ = bw + (P) * 2048;                                                   \
    __builtin_amdgcn_global_load_lds(                                                 \
        (const __attribute__((address_space(1))) unsigned int*)(g_),                  \
        (__attribute__((address_space(3))) unsigned int*)(l_), 16, 0, 0);             \
    __builtin_amdgcn_global_load_lds(                                                 \
        (const __attribute__((address_space(1))) unsigned int*)(g_ + 8192),           \
        (__attribute__((address_space(3))) unsigned int*)(l_ + 512), 16, 0, 0);       \
    __builtin_amdgcn_global_load_lds(                                                 \
        (const __attribute__((address_space(1))) unsigned int*)(g_ + 16384),          \
        (__attribute__((address_space(3))) unsigned int*)(l_ + 1024), 16, 0, 0);      \
    __builtin_amdgcn_global_load_lds(                                                 \
        (const __attribute__((address_space(1))) unsigned int*)(g_ + 24576),          \
        (__attribute__((address_space(3))) unsigned int*)(l_ + 1536), 16, 0, 0);      \
  } while (0)

// consume one ks-step: wait its DMA (counted), ds_read B+A frags, 16 MFMA
#define KSHALF(KS, P, WN)                                                             \
  do {                                                                                \
    asm volatile("s_waitcnt vmcnt(" WN ")" ::: "memory");                             \
    __builtin_amdgcn_sched_barrier(0);                                                \
    const _Float16* bp_ = bw + (P) * 2048 + boffh;                                    \
    f16x8 q0 = *(const f16x8*)(bp_);                                                  \
    f16x8 q1 = *(const f16x8*)(bp_ + 512);                                            \
    f16x8 q2 = *(const f16x8*)(bp_ + 1024);                                           \
    f16x8 q3 = *(const f16x8*)(bp_ + 1536);                                           \
    const char* ap_ = (const char*)Ah + lr * 512 + (((KS) * 64 + lg * 16) ^ swz);     \
    f16x8 p0 = *(const f16x8*)(ap_);                                                  \
    f16x8 p1 = *(const f16x8*)(ap_ + 8192);                                           \
    f16x8 p2 = *(const f16x8*)(ap_ + 16384);                                          \
    f16x8 p3 = *(const f16x8*)(ap_ + 24576);                                          \
    acc[0][0] = __builtin_amdgcn_mfma_f32_16x16x32_f16(p0, q0, acc[0][0], 0, 0, 0);   \
    acc[0][1] = __builtin_amdgcn_mfma_f32_16x16x32_f16(p1, q0, acc[0][1], 0, 0, 0);   \
    acc[0][2] = __builtin_amdgcn_mfma_f32_16x16x32_f16(p2, q0, acc[0][2], 0, 0, 0);   \
    acc[0][3] = __builtin_amdgcn_mfma_f32_16x16x32_f16(p3, q0, acc[0][3], 0, 0, 0);   \
    acc[1][0] = __builtin_amdgcn_mfma_f32_16x16x32_f16(p0, q1, acc[1][0], 0, 0, 0);   \
    acc[1][1] = __builtin_amdgcn_mfma_f32_16x16x32_f16(p1, q1, acc[1][1], 0, 0, 0);   \
    acc[1][2] = __builtin_amdgcn_mfma_f32_16x16x32_f16(p2, q1, acc[1][2], 0, 0, 0);   \
    acc[1][3] = __builtin_amdgcn_mfma_f32_16x16x32_f16(p3, q1, acc[1][3], 0, 0, 0);   \
    acc[2][0] = __builtin_amdgcn_mfma_f32_16x16x32_f16(p0, q2, acc[2][0], 0, 0, 0);   \
    acc[2][1] = __builtin_amdgcn_mfma_f32_16x16x32_f16(p1, q2, acc[2][1], 0, 0, 0);   \
    acc[2][2] = __builtin_amdgcn_mfma_f32_16x16x32_f16(p2, q2, acc[2][2], 0, 0, 0);   \
    acc[2][3] = __builtin_amdgcn_mfma_f32_16x16x32_f16(p3, q2, acc[2][3], 0, 0, 0);   \
    acc[3][0] = __builtin_amdgcn_mfma_f32_16x16x32_f16(p0, q3, acc[3][0], 0, 0, 0);   \
    acc[3][1] = __builtin_amdgcn_mfma_f32_16x16x32_f16(p1, q3, acc[3][1], 0, 0, 0);   \
    acc[3][2] = __builtin_amdgcn_mfma_f32_16x16x32_f16(p2, q3, acc[3][2], 0, 0, 0);   \
    acc[3][3] = __builtin_amdgcn_mfma_f32_16x16x32_f16(p3, q3, acc[3][3], 0, 0, 0);   \
  } while (0)

  size_t chb = (size_t)w * 131072;  // wave's ctp byte base (col-tile w*16), ch adds 32768
  DMA4(chb, 0, 0);                  // prologue: ks0 -> buf0, ks1 -> buf1
  DMA4(chb, 1, 1);
#pragma unroll 1
  for (int ch = 0; ch < 4; ++ch) {
    const int ccb = w * 256 + ch * 64;
    f32x4 acc[4][4];                // [ct][rt]
#pragma unroll
    for (int ct = 0; ct < 4; ++ct)
#pragma unroll
      for (int rt = 0; rt < 4; ++rt) acc[ct][rt] = (f32x4){0.f, 0.f, 0.f, 0.f};

    KSHALF(0, 0, "4");  DMA4(chb, 2, 0);
    KSHALF(1, 1, "4");  DMA4(chb, 3, 1);
    KSHALF(2, 0, "4");  DMA4(chb, 4, 0);
    KSHALF(3, 1, "4");  DMA4(chb, 5, 1);
    KSHALF(4, 0, "4");  DMA4(chb, 6, 0);
    KSHALF(5, 1, "4");  DMA4(chb, 7, 1);
    KSHALF(6, 0, "4");
    if (ch < 3) {                   // prefetch next ch before last half + fold
      DMA4(chb + 32768, 0, 0);
      KSHALF(7, 1, "4");
      DMA4(chb + 32768, 1, 1);
    } else {
      KSHALF(7, 1, "0");
    }

    // fold into running best / 2nd-best (cols ascend over time -> first-min tiebreak)
#pragma unroll
    for (int ct = 0; ct < 4; ++ct) {
      const int col = ccb + ct * 16 + lr;
      const float cq = csql[col];
#pragma unroll
      for (int rt = 0; rt < 4; ++rt)
#pragma unroll
        for (int rg = 0; rg < 4; ++rg) {
          float d = cq - 2.f * acc[ct][rt][rg];
          if (d < b1[rt][rg]) {
            b2v[rt][rg] = b1[rt][rg];
            b1[rt][rg] = d;
            bk[rt][rg] = col;
          } else if (d < b2v[rt][rg]) {
            b2v[rt][rg] = d;
          }
        }
    }
    chb += 32768;
  }
#undef DMA4
#undef KSHALF

  // reduce over the 16 k-lanes of each group
#pragma unroll
  for (int rt = 0; rt < 4; ++rt)
#pragma unroll
    for (int rg = 0; rg < 4; ++rg) {
      float v1 = b1[rt][rg], v2 = b2v[rt][rg];
      int kk = bk[rt][rg];
#pragma unroll
      for (int off = 8; off >= 1; off >>= 1) {
        float o1 = __shfl_xor(v1, off);
        int ok = __shfl_xor(kk, off);
        float o2 = __shfl_xor(v2, off);
        float nb2 = fminf(fmaxf(v1, o1), fminf(v2, o2));
        if (o1 < v1 || (o1 == v1 && ok < kk)) { v1 = o1; kk = ok; }
        v2 = nb2;
      }
      if (lr == 0) {
        int row = rt * 16 + lg * 4 + rg;
        red1[w][row] = v1;
        redk[w][row] = kk;
        red2[w][row] = v2;
      }
    }
  __syncthreads();
  if (t < 64) {
    float v1 = red1[0][t], v2 = red2[0][t];
    int kk = redk[0][t];
#pragma unroll
    for (int wi = 1; wi < 4; ++wi) {
      float o1 = red1[wi][t], o2 = red2[wi][t];
      int ok = redk[wi][t];
      float nb2 = fminf(fmaxf(v1, o1), fminf(v2, o2));
      if (o1 < v1 || (o1 == v1 && ok < kk)) { v1 = o1; kk = ok; }
      v2 = nb2;
    }
    ind[n0 + t] = kk;
    atomicAdd(&counts[kk], 1u);
    if (v2 - v1 < DELTA) {
      unsigned int p = atomicAdd(flagcnt, 1u);
      flaglist[p] = n0 + t;
    }
  }
}

// ---------------- exact fp32 re-argmin for low-margin rows ----------------
__global__ __launch_bounds__(256) void fixup_kernel(
    const _Float16* __restrict__ xh, const _Float16* __restrict__ xl,
    const float* __restrict__ cent, const float* __restrict__ csq,
    const int* __restrict__ flaglist, const unsigned int* __restrict__ flagcnt,
    int* __restrict__ ind, unsigned int* __restrict__ counts) {
  const int t = threadIdx.x;
  const int nf = (int)*flagcnt;
  __shared__ float xrow[256];
  __shared__ float rv[256];
  __shared__ int rk[256];
  for (int ii = blockIdx.x; ii < nf; ii += gridDim.x) {
    __syncthreads();
    int row = flaglist[ii];
    xrow[t] = (float)xh[(size_t)row * 256 + t] + (float)xl[(size_t)row * 256 + t];
    __syncthreads();
    float a0 = 0.f, a1 = 0.f, a2 = 0.f, a3 = 0.f;
#pragma unroll 8
    for (int f = 0; f < 256; ++f) {
      float xs = xrow[f];
      const float* cr = cent + (size_t)f * 1024 + t;
      a0 += xs * cr[0];
      a1 += xs * cr[256];
      a2 += xs * cr[512];
      a3 += xs * cr[768];
    }
    float bd = csq[t] - 2.f * a0;
    int bkk = t;
    float d1 = csq[t + 256] - 2.f * a1;
    if (d1 < bd) { bd = d1; bkk = t + 256; }
    float d2 = csq[t + 512] - 2.f * a2;
    if (d2 < bd) { bd = d2; bkk = t + 512; }
    float d3 = csq[t + 768] - 2.f * a3;
    if (d3 < bd) { bd = d3; bkk = t + 768; }
    rv[t] = bd;
    rk[t] = bkk;
    __syncthreads();
    for (int off = 128; off >= 1; off >>= 1) {
      if (t < off) {
        float ov = rv[t + off];
        int ok = rk[t + off];
        if (ov < rv[t] || (ov == rv[t] && ok < rk[t])) { rv[t] = ov; rk[t] = ok; }
      }
      __syncthreads();
    }
    if (t == 0) {
      int newk = rk[0];
      int oldk = ind[row];
      if (newk != oldk) {
        ind[row] = newk;
        atomicAdd(&counts[oldk], 0xFFFFFFFFu);  // -1
        atomicAdd(&counts[newk], 1u);
      }
    }
  }
}

// ---------------- single-wave: cluster-size EMA/Laplace norm + exclusive scan ----
__global__ __launch_bounds__(64) void csnorm_scan_kernel(
    const float* __restrict__ cs, const unsigned int* __restrict__ counts,
    float* __restrict__ icn, unsigned int* __restrict__ offsets,
    unsigned int* __restrict__ cursor) {
  const int t = threadIdx.x;  // 0..63, each owns 16 clusters
  unsigned int cl[16];
  float csl[16];
  unsigned int s = 0;
  float css = 0.f;
#pragma unroll
  for (int j = 0; j < 16; ++j) {
    cl[j] = counts[t * 16 + j];
    s += cl[j];
    csl[j] = cs[t * 16 + j];
    css += csl[j];
  }
  unsigned int incl = s;
#pragma unroll
  for (int off = 1; off < 64; off <<= 1) {
    unsigned int v = __shfl_up(incl, off);
    if (t >= off) incl += v;
  }
  unsigned int run = incl - s;  // exclusive prefix
  float tot = css;
#pragma unroll
  for (int off = 32; off >= 1; off >>= 1) tot += __shfl_xor(tot, off);
  const float n = DECAY * tot + (1.f - DECAY) * 65536.f;  // sum of new_cs (counts sum = N)
#pragma unroll
  for (int j = 0; j < 16; ++j) {
    int k = t * 16 + j;
    offsets[k] = run;
    cursor[k] = run;
    float ncs = DECAY * csl[j] + (1.f - DECAY) * (float)cl[j];
    float csn = (ncs + EPSF) / (n + 1024.f * EPSF) * n;
    icn[k] = 1.f / csn;
    run += cl[j];
  }
  if (t == 63) offsets[1024] = run;
}

// ---------------- scatter row ids into cluster-ordered list ----------------
__global__ void scatter_kernel(const int* __restrict__ ind, unsigned int* __restrict__ cursor,
                               int* __restrict__ rowlist) {
  int n = blockIdx.x * 256 + threadIdx.x;
  int k = ind[n];
  unsigned int pos = atomicAdd(&cursor[k], 1u);
  rowlist[pos] = n;
}

// ---------------- balanced segment-sum: position-partitioned + boundary flush ----
// xh-only sum: dropped xl contribution error ~1e-4 relative on output (<<2.88 thr).
__global__ __launch_bounds__(256) void sumflush_kernel(
    const _Float16* __restrict__ xh, const int* __restrict__ rowlist,
    const int* __restrict__ ind, float* __restrict__ sums) {
  __shared__ int rl[64];
  __shared__ int kl[64];
  const int t = threadIdx.x;
  const int sub = t >> 6, lane = t & 63;
  const int p0 = blockIdx.x * 64;
  if (t < 64) {
    int r = rowlist[p0 + t];
    rl[t] = r;
    kl[t] = ind[r];
  }
  __syncthreads();
  float a0 = 0.f, a1 = 0.f, a2 = 0.f, a3 = 0.f;
  int curk = kl[sub * 16];
#pragma unroll
  for (int i = 0; i < 16; ++i) {
    int p = sub * 16 + i;
    int k = kl[p];
    if (k != curk) {  // wave-uniform branch (k uniform across the wave)
      float* dst = &sums[(size_t)curk * 256 + lane * 4];
      atomicAdd(&dst[0], a0);
      atomicAdd(&dst[1], a1);
      atomicAdd(&dst[2], a2);
      atomicAdd(&dst[3], a3);
      a0 = a1 = a2 = a3 = 0.f;
      curk = k;
    }
    int r = rl[p];
    uint2 vh = *(const uint2*)&((const unsigned int*)xh)[(size_t)r * 128 + lane * 2];
    a0 += h_val((unsigned short)(vh.x & 0xFFFF));
    a1 += h_val((unsigned short)(vh.x >> 16));
    a2 += h_val((unsigned short)(vh.y & 0xFFFF));
    a3 += h_val((unsigned short)(vh.y >> 16));
  }
  float* dst = &sums[(size_t)curk * 256 + lane * 4];
  atomicAdd(&dst[0], a0);
  atomicAdd(&dst[1], a1);
  atomicAdd(&dst[2], a2);
  atomicAdd(&dst[3], a3);
}

// ---------------- centroid EMA + scale, [k][f] -> [f][k] transpose ----------------
__global__ __launch_bounds__(256) void newcentT_kernel(
    const float* __restrict__ sums, const float* __restrict__ avg,
    const float* __restrict__ icn, float* __restrict__ nc) {
  __shared__ float tl[32][33];
  const int t = threadIdx.x;
  const int k0 = (blockIdx.x & 31) * 32, f0 = (blockIdx.x >> 5) * 32;
#pragma unroll
  for (int i = 0; i < 4; ++i) {
    int ki = (t >> 5) + i * 8, fi = t & 31;
    tl[ki][fi] = sums[(size_t)(k0 + ki) * 256 + f0 + fi];
  }
  __syncthreads();
#pragma unroll
  for (int i = 0; i < 4; ++i) {
    int fi = (t >> 5) + i * 8, ki = t & 31;
    size_t idx = (size_t)(f0 + fi) * 1024 + k0 + ki;
    nc[idx] = (DECAY * avg[idx] + (1.f - DECAY) * tl[ki][fi]) * icn[k0 + ki];
  }
}

// ---------------- gather output: out[b][c][h][w] = nc[c][ind[n(b,w,h)]] ----------------
__global__ void gather_kernel(const float* __restrict__ nc, const int* __restrict__ ind,
                              float* __restrict__ out) {
  __shared__ int ip[1024];
  int b = blockIdx.x >> 3;
  int cg = (blockIdx.x & 7) * 32;
  int t = threadIdx.x;
#pragma unroll
  for (int j = 0; j < 4; ++j) {
    int p = t + j * 256;                 // p = h*32 + w
    int r = ((p & 31) << 5) | (p >> 5);  // r = w*32 + h
    ip[p] = ind[(b << 10) + r];
  }
  __syncthreads();
  for (int c = cg; c < cg + 32; ++c) {
    const float* row = nc + (size_t)c * 1024;
#pragma unroll
    for (int j = 0; j < 4; ++j) {
      int p = t + j * 256;
      out[((size_t)(b * 256 + c) << 10) + p] = row[ip[p]];
    }
  }
}

extern "C" void kernel_launch(void* const* d_in, const int* in_sizes, int n_in,
                              void* d_out, int out_size, void* d_ws, size_t ws_size,
                              hipStream_t stream) {
  const float* x = (const float*)d_in[0];
  const float* cent = (const float*)d_in[1];
  const float* cs = (const float*)d_in[2];
  const float* avg = (const float*)d_in[3];
  float* out = (float*)d_out;

  char* ws = (char*)d_ws;
  _Float16* xh = (_Float16*)ws;                              // 32 MB
  _Float16* xl = (_Float16*)(ws + 33554432);                 // 32 MB
  _Float16* ctp = (_Float16*)(ws + 67108864);                // 512 KB packed B
  float* nc = (float*)(ws + 67108864);                       // 1 MB (aliases ctp; disjoint lifetime)
  unsigned int* counts = (unsigned int*)(ws + 68157440);     // 4 KB  ┐
  unsigned int* flagcnt = (unsigned int*)(ws + 68161536);    // 4 KB  │ one contiguous memset
  float* sums = (float*)(ws + 68165632);                     // 1 MB  ┘
  float* csqv = (float*)(ws + 69214208);                     // 4 KB
  float* icn = (float*)(ws + 69218304);                      // 4 KB
  unsigned int* offsets = (unsigned int*)(ws + 69222400);    // 8 KB (1025 used)
  unsigned int* cursor = (unsigned int*)(ws + 69230592);     // 4 KB
  int* ind = (int*)(ws + 69234688);                          // 256 KB
  int* flaglist = (int*)(ws + 69496832);                     // 256 KB (aliases rowlist)
  int* rowlist = (int*)(ws + 69496832);

  hipMemsetAsync(counts, 0, 1056768, stream);  // counts + flagcnt + sums

  csq_kernel<<<16, 256, 0, stream>>>(cent, csqv);
  centT_kernel<<<256, 256, 0, stream>>>(cent, ctp);
  transpose_kernel<<<4096, 256, 0, stream>>>(x, xh, xl);
  mfma_argmin_kernel<<<1024, 256, 0, stream>>>(xh, ctp, csqv, ind, flaglist, flagcnt, counts);
  fixup_kernel<<<128, 256, 0, stream>>>(xh, xl, cent, csqv, flaglist, flagcnt, ind, counts);
  csnorm_scan_kernel<<<1, 64, 0, stream>>>(cs, counts, icn, offsets, cursor);
  scatter_kernel<<<256, 256, 0, stream>>>(ind, cursor, rowlist);
  sumflush_kernel<<<1024, 256, 0, stream>>>(xh, rowlist, ind, sums);
  newcentT_kernel<<<256, 256, 0, stream>>>(sums, avg, icn, nc);
  gather_kernel<<<512, 256, 0, stream>>>(nc, ind, out);
}

// Round 13
// 265.241 us; speedup vs baseline: 1.4881x; 1.0476x over previous
//
#include <hip/hip_runtime.h>

// x: [64, 256, 32, 32] f32 ; centroids: [256, 1024] ; cluster_size: [1024] ;
// centroids_avg: [256, 1024]
// N = 65536 rows, F = 256, K = 1024.  xf row n = (b*32 + w)*32 + h

#define DECAY 0.99f
#define EPSF 1e-5f
#define DELTA 0.05f

typedef _Float16 f16x8 __attribute__((ext_vector_type(8)));
typedef float f32x4 __attribute__((ext_vector_type(4)));

static __device__ __forceinline__ unsigned short h_bits(_Float16 h) {
  return __builtin_bit_cast(unsigned short, h);
}
static __device__ __forceinline__ float h_val(unsigned short u) {
  return (float)__builtin_bit_cast(_Float16, u);
}

// ---------------- centroids -> packed fp16 B-frag layout + fused csq + zeroing ----
// ctp element for (k, f): colt=k>>4, lr=k&15, ks=f>>5, lg=(f>>3)&3, e=f&7
// half index = colt*4096 + ks*512 + lr*32 + lg*8 + e
// Blocks with f0==0 (bid<32) also compute csq for their 32 k (deterministic order).
// Block 32 zeroes counts+flagcnt.
__global__ void centT_kernel(const float* __restrict__ cent, _Float16* __restrict__ ctp,
                             float* __restrict__ csq, unsigned int* __restrict__ counts,
                             unsigned int* __restrict__ flagcnt) {
  __shared__ float tl[32][33];
  const int bid = blockIdx.x;
  const int f0 = (bid >> 5) * 32, k0 = (bid & 31) * 32;
  const int t = threadIdx.x;
#pragma unroll
  for (int i = 0; i < 4; ++i) {
    int fi = (t >> 5) + i * 8, ki = t & 31;
    tl[fi][ki] = cent[(size_t)(f0 + fi) * 1024 + k0 + ki];
  }
  __syncthreads();
#pragma unroll
  for (int i = 0; i < 4; ++i) {
    int ki = (t >> 5) + i * 8, fi = t & 31;
    int k = k0 + ki, f = f0 + fi;
    _Float16 h = (_Float16)tl[fi][ki];
    size_t idx = (size_t)(k >> 4) * 4096 + (size_t)(f >> 5) * 512 +
                 (size_t)(k & 15) * 32 + (size_t)((f >> 3) & 3) * 8 + (f & 7);
    ctp[idx] = h;
  }
  if (bid < 32) {  // full-column csq for k0..k0+31, fixed summation order
    __shared__ float red[8][32];
    const int kk = k0 + (t & 31);
    const int fg = t >> 5;
    float s = 0.f;
    for (int f = fg * 32; f < fg * 32 + 32; ++f) {
      float v = cent[(size_t)f * 1024 + kk];
      s += v * v;
    }
    red[fg][t & 31] = s;
    __syncthreads();
    if (t < 32) {
      float tot = 0.f;
#pragma unroll
      for (int g = 0; g < 8; ++g) tot += red[g][t];
      csq[k0 + t] = tot;
    }
  }
  if (bid == 32) {
    counts[t] = 0u;
    counts[t + 256] = 0u;
    counts[t + 512] = 0u;
    counts[t + 768] = 0u;
    if (t == 0) *flagcnt = 0u;
  }
}

// ---------------- transpose x -> xh fp16 [65536][256] ----------------
__global__ void transpose_kernel(const float* __restrict__ x, _Float16* __restrict__ xh) {
  __shared__ float tile[64][65];
  int bid = blockIdx.x;
  int pt = bid & 15, ct = (bid >> 4) & 3, b = bid >> 6;
  int c0 = ct * 64, p0 = pt * 64;
  int t = threadIdx.x;
#pragma unroll
  for (int i = 0; i < 16; ++i) {
    int idx = t + i * 256;
    int ci = idx >> 6, pi = idx & 63;
    tile[ci][pi] = x[((size_t)(b * 256 + c0 + ci) << 10) + p0 + pi];
  }
  __syncthreads();
#pragma unroll
  for (int i = 0; i < 8; ++i) {
    int idx = t + i * 256;            // 2048 = 64 p x 32 c-pairs
    int pi = idx >> 5, cp = idx & 31;
    int p = p0 + pi;
    int r = ((p & 31) << 5) | (p >> 5);
    float v0 = tile[cp * 2][pi], v1 = tile[cp * 2 + 1][pi];
    unsigned int uh = (unsigned int)h_bits((_Float16)v0) |
                      ((unsigned int)h_bits((_Float16)v1) << 16);
    ((unsigned int*)xh)[((size_t)((b << 10) + r)) * 128 + ct * 32 + cp] = uh;
  }
}

// ---------------- MFMA distance + argmin + 2nd-best margin (R11, frozen) ----------
__global__ __launch_bounds__(256, 2) void mfma_argmin_kernel(
    const _Float16* __restrict__ xh, const _Float16* __restrict__ ctp,
    const float* __restrict__ csq, int* __restrict__ ind,
    int* __restrict__ flaglist, unsigned int* __restrict__ flagcnt,
    unsigned int* __restrict__ counts) {
  __shared__ _Float16 Ah[64 * 256];         // 32 KB, 512 B/row, XOR-swizzled
  __shared__ _Float16 Bst[4 * 2 * 4 * 512]; // 32 KB: [wave][parity][ct][512 halfs]
  __shared__ float csql[1024];
  __shared__ float red1[4][64], red2[4][64];
  __shared__ int redk[4][64];
  const int t = threadIdx.x;
  const int lane = t & 63, w = t >> 6;
  const int lr = lane & 15, lg = lane >> 4;
  const int n0 = blockIdx.x * 64;

#pragma unroll
  for (int i = 0; i < 4; ++i) csql[t + i * 256] = csq[t + i * 256];
#pragma unroll
  for (int i = 0; i < 8; ++i) {
    int idx = t + i * 256;            // 2048 = 64 rows x 32 16B-chunks
    int row = idx >> 5, c16 = (idx & 31) * 16;
    int sw = c16 ^ ((row & 7) << 4);
    *(f16x8*)((char*)Ah + row * 512 + sw) =
        *(const f16x8*)((const char*)xh + (size_t)(n0 + row) * 512 + c16);
  }
  __syncthreads();   // drains vmcnt: staging loads retired before DMA counting starts

  float b1[4][4], b2v[4][4];
  int bk[4][4];
#pragma unroll
  for (int rt = 0; rt < 4; ++rt)
#pragma unroll
    for (int rg = 0; rg < 4; ++rg) { b1[rt][rg] = 3.4e38f; b2v[rt][rg] = 3.4e38f; bk[rt][rg] = 0; }

  const int swz = (lr & 7) << 4;
  const int boffh = (lr * 4 + lg) * 8;      // this lane's frag (halfs) within a 1KB chunk
  const size_t lgo = (size_t)lane * 16;     // DMA: lane's byte offset within a chunk
  _Float16* bw = &Bst[w * 4096];            // wave-private 8 KB region

#define DMA4(CHB, KS, P)                                                              \
  do {                                                                                \
    const char* g_ = (const char*)ctp + (CHB) + (size_t)(KS) * 1024 + lgo;            \
    _Float16* l_ = bw + (P) * 2048;                                                   \
    __builtin_amdgcn_global_load_lds(                                                 \
        (const __attribute__((address_space(1))) unsigned int*)(g_),                  \
        (__attribute__((address_space(3))) unsigned int*)(l_), 16, 0, 0);             \
    __builtin_amdgcn_global_load_lds(                                                 \
        (const __attribute__((address_space(1))) unsigned int*)(g_ + 8192),           \
        (__attribute__((address_space(3))) unsigned int*)(l_ + 512), 16, 0, 0);       \
    __builtin_amdgcn_global_load_lds(                                                 \
        (const __attribute__((address_space(1))) unsigned int*)(g_ + 16384),          \
        (__attribute__((address_space(3))) unsigned int*)(l_ + 1024), 16, 0, 0);      \
    __builtin_amdgcn_global_load_lds(                                                 \
        (const __attribute__((address_space(1))) unsigned int*)(g_ + 24576),          \
        (__attribute__((address_space(3))) unsigned int*)(l_ + 1536), 16, 0, 0);      \
  } while (0)

#define KSHALF(KS, P, WN)                                                             \
  do {                                                                                \
    asm volatile("s_waitcnt vmcnt(" WN ")" ::: "memory");                             \
    __builtin_amdgcn_sched_barrier(0);                                                \
    const _Float16* bp_ = bw + (P) * 2048 + boffh;                                    \
    f16x8 q0 = *(const f16x8*)(bp_);                                                  \
    f16x8 q1 = *(const f16x8*)(bp_ + 512);                                            \
    f16x8 q2 = *(const f16x8*)(bp_ + 1024);                                           \
    f16x8 q3 = *(const f16x8*)(bp_ + 1536);                                           \
    const char* ap_ = (const char*)Ah + lr * 512 + (((KS) * 64 + lg * 16) ^ swz);     \
    f16x8 p0 = *(const f16x8*)(ap_);                                                  \
    f16x8 p1 = *(const f16x8*)(ap_ + 8192);                                           \
    f16x8 p2 = *(const f16x8*)(ap_ + 16384);                                          \
    f16x8 p3 = *(const f16x8*)(ap_ + 24576);                                          \
    acc[0][0] = __builtin_amdgcn_mfma_f32_16x16x32_f16(p0, q0, acc[0][0], 0, 0, 0);   \
    acc[0][1] = __builtin_amdgcn_mfma_f32_16x16x32_f16(p1, q0, acc[0][1], 0, 0, 0);   \
    acc[0][2] = __builtin_amdgcn_mfma_f32_16x16x32_f16(p2, q0, acc[0][2], 0, 0, 0);   \
    acc[0][3] = __builtin_amdgcn_mfma_f32_16x16x32_f16(p3, q0, acc[0][3], 0, 0, 0);   \
    acc[1][0] = __builtin_amdgcn_mfma_f32_16x16x32_f16(p0, q1, acc[1][0], 0, 0, 0);   \
    acc[1][1] = __builtin_amdgcn_mfma_f32_16x16x32_f16(p1, q1, acc[1][1], 0, 0, 0);   \
    acc[1][2] = __builtin_amdgcn_mfma_f32_16x16x32_f16(p2, q1, acc[1][2], 0, 0, 0);   \
    acc[1][3] = __builtin_amdgcn_mfma_f32_16x16x32_f16(p3, q1, acc[1][3], 0, 0, 0);   \
    acc[2][0] = __builtin_amdgcn_mfma_f32_16x16x32_f16(p0, q2, acc[2][0], 0, 0, 0);   \
    acc[2][1] = __builtin_amdgcn_mfma_f32_16x16x32_f16(p1, q2, acc[2][1], 0, 0, 0);   \
    acc[2][2] = __builtin_amdgcn_mfma_f32_16x16x32_f16(p2, q2, acc[2][2], 0, 0, 0);   \
    acc[2][3] = __builtin_amdgcn_mfma_f32_16x16x32_f16(p3, q2, acc[2][3], 0, 0, 0);   \
    acc[3][0] = __builtin_amdgcn_mfma_f32_16x16x32_f16(p0, q3, acc[3][0], 0, 0, 0);   \
    acc[3][1] = __builtin_amdgcn_mfma_f32_16x16x32_f16(p1, q3, acc[3][1], 0, 0, 0);   \
    acc[3][2] = __builtin_amdgcn_mfma_f32_16x16x32_f16(p2, q3, acc[3][2], 0, 0, 0);   \
    acc[3][3] = __builtin_amdgcn_mfma_f32_16x16x32_f16(p3, q3, acc[3][3], 0, 0, 0);   \
  } while (0)

  size_t chb = (size_t)w * 131072;  // wave's ctp byte base (col-tile w*16), ch adds 32768
  DMA4(chb, 0, 0);
  DMA4(chb, 1, 1);
#pragma unroll 1
  for (int ch = 0; ch < 4; ++ch) {
    const int ccb = w * 256 + ch * 64;
    f32x4 acc[4][4];                // [ct][rt]
#pragma unroll
    for (int ct = 0; ct < 4; ++ct)
#pragma unroll
      for (int rt = 0; rt < 4; ++rt) acc[ct][rt] = (f32x4){0.f, 0.f, 0.f, 0.f};

    KSHALF(0, 0, "4");  DMA4(chb, 2, 0);
    KSHALF(1, 1, "4");  DMA4(chb, 3, 1);
    KSHALF(2, 0, "4");  DMA4(chb, 4, 0);
    KSHALF(3, 1, "4");  DMA4(chb, 5, 1);
    KSHALF(4, 0, "4");  DMA4(chb, 6, 0);
    KSHALF(5, 1, "4");  DMA4(chb, 7, 1);
    KSHALF(6, 0, "4");
    if (ch < 3) {
      DMA4(chb + 32768, 0, 0);
      KSHALF(7, 1, "4");
      DMA4(chb + 32768, 1, 1);
    } else {
      KSHALF(7, 1, "0");
    }

#pragma unroll
    for (int ct = 0; ct < 4; ++ct) {
      const int col = ccb + ct * 16 + lr;
      const float cq = csql[col];
#pragma unroll
      for (int rt = 0; rt < 4; ++rt)
#pragma unroll
        for (int rg = 0; rg < 4; ++rg) {
          float d = cq - 2.f * acc[ct][rt][rg];
          if (d < b1[rt][rg]) {
            b2v[rt][rg] = b1[rt][rg];
            b1[rt][rg] = d;
            bk[rt][rg] = col;
          } else if (d < b2v[rt][rg]) {
            b2v[rt][rg] = d;
          }
        }
    }
    chb += 32768;
  }
#undef DMA4
#undef KSHALF

#pragma unroll
  for (int rt = 0; rt < 4; ++rt)
#pragma unroll
    for (int rg = 0; rg < 4; ++rg) {
      float v1 = b1[rt][rg], v2 = b2v[rt][rg];
      int kk = bk[rt][rg];
#pragma unroll
      for (int off = 8; off >= 1; off >>= 1) {
        float o1 = __shfl_xor(v1, off);
        int ok = __shfl_xor(kk, off);
        float o2 = __shfl_xor(v2, off);
        float nb2 = fminf(fmaxf(v1, o1), fminf(v2, o2));
        if (o1 < v1 || (o1 == v1 && ok < kk)) { v1 = o1; kk = ok; }
        v2 = nb2;
      }
      if (lr == 0) {
        int row = rt * 16 + lg * 4 + rg;
        red1[w][row] = v1;
        redk[w][row] = kk;
        red2[w][row] = v2;
      }
    }
  __syncthreads();
  if (t < 64) {
    float v1 = red1[0][t], v2 = red2[0][t];
    int kk = redk[0][t];
#pragma unroll
    for (int wi = 1; wi < 4; ++wi) {
      float o1 = red1[wi][t], o2 = red2[wi][t];
      int ok = redk[wi][t];
      float nb2 = fminf(fmaxf(v1, o1), fminf(v2, o2));
      if (o1 < v1 || (o1 == v1 && ok < kk)) { v1 = o1; kk = ok; }
      v2 = nb2;
    }
    ind[n0 + t] = kk;
    atomicAdd(&counts[kk], 1u);
    if (v2 - v1 < DELTA) {
      unsigned int p = atomicAdd(flagcnt, 1u);
      flaglist[p] = n0 + t;
    }
  }
}

// ---------------- exact fp32 re-argmin, batched 4 rows per cent-pass ----------------
__global__ __launch_bounds__(256) void fixup_kernel(
    const float* __restrict__ x, const float* __restrict__ cent,
    const float* __restrict__ csq, const int* __restrict__ flaglist,
    const unsigned int* __restrict__ flagcnt, int* __restrict__ ind,
    unsigned int* __restrict__ counts) {
  const int t = threadIdx.x;
  const int nf = (int)*flagcnt;
  __shared__ float xrow[4][256];
  __shared__ int rows[4];
  __shared__ float rv[256];
  __shared__ int rk[256];
  for (int base = blockIdx.x * 4; base < nf; base += gridDim.x * 4) {
    const int cnt = min(4, nf - base);
    __syncthreads();
    if (t < 4) rows[t] = flaglist[base + (t < cnt ? t : 0)];
    __syncthreads();
#pragma unroll
    for (int j = 0; j < 4; ++j) {
      int row = rows[j];
      int b = row >> 10, r = row & 1023, wq = r >> 5, h = r & 31;
      xrow[j][t] = x[((size_t)(b * 256 + t) << 10) + h * 32 + wq];  // exact fp32
    }
    __syncthreads();
    float a[4][4];
#pragma unroll
    for (int j = 0; j < 4; ++j)
#pragma unroll
      for (int q = 0; q < 4; ++q) a[j][q] = 0.f;
#pragma unroll 4
    for (int f = 0; f < 256; ++f) {
      const float* cr = cent + (size_t)f * 1024 + t;
      float c0 = cr[0], c1 = cr[256], c2 = cr[512], c3 = cr[768];
#pragma unroll
      for (int j = 0; j < 4; ++j) {
        float xv = xrow[j][f];
        a[j][0] += xv * c0;
        a[j][1] += xv * c1;
        a[j][2] += xv * c2;
        a[j][3] += xv * c3;
      }
    }
    for (int j = 0; j < cnt; ++j) {
      float bd = csq[t] - 2.f * a[j][0];
      int bkk = t;
      float d1 = csq[t + 256] - 2.f * a[j][1];
      if (d1 < bd) { bd = d1; bkk = t + 256; }
      float d2 = csq[t + 512] - 2.f * a[j][2];
      if (d2 < bd) { bd = d2; bkk = t + 512; }
      float d3 = csq[t + 768] - 2.f * a[j][3];
      if (d3 < bd) { bd = d3; bkk = t + 768; }
      rv[t] = bd;
      rk[t] = bkk;
      __syncthreads();
      for (int off = 128; off >= 1; off >>= 1) {
        if (t < off) {
          float ov = rv[t + off];
          int ok = rk[t + off];
          if (ov < rv[t] || (ov == rv[t] && ok < rk[t])) { rv[t] = ov; rk[t] = ok; }
        }
        __syncthreads();
      }
      if (t == 0) {
        int newk = rk[0], row = rows[j], oldk = ind[row];
        if (newk != oldk) {
          ind[row] = newk;
          atomicAdd(&counts[oldk], 0xFFFFFFFFu);  // -1
          atomicAdd(&counts[newk], 1u);
        }
      }
      __syncthreads();
    }
  }
}

// ---------------- single-wave: cluster-size EMA/Laplace norm + exclusive scan ----
__global__ __launch_bounds__(64) void csnorm_scan_kernel(
    const float* __restrict__ cs, const unsigned int* __restrict__ counts,
    float* __restrict__ icn, unsigned int* __restrict__ offsets,
    unsigned int* __restrict__ cursor) {
  const int t = threadIdx.x;  // 0..63, each owns 16 clusters
  unsigned int cl[16];
  float csl[16];
  unsigned int s = 0;
  float css = 0.f;
#pragma unroll
  for (int j = 0; j < 16; ++j) {
    cl[j] = counts[t * 16 + j];
    s += cl[j];
    csl[j] = cs[t * 16 + j];
    css += csl[j];
  }
  unsigned int incl = s;
#pragma unroll
  for (int off = 1; off < 64; off <<= 1) {
    unsigned int v = __shfl_up(incl, off);
    if (t >= off) incl += v;
  }
  unsigned int run = incl - s;  // exclusive prefix
  float tot = css;
#pragma unroll
  for (int off = 32; off >= 1; off >>= 1) tot += __shfl_xor(tot, off);
  const float n = DECAY * tot + (1.f - DECAY) * 65536.f;  // counts sum = N
#pragma unroll
  for (int j = 0; j < 16; ++j) {
    int k = t * 16 + j;
    offsets[k] = run;
    cursor[k] = run;
    float ncs = DECAY * csl[j] + (1.f - DECAY) * (float)cl[j];
    float csn = (ncs + EPSF) / (n + 1024.f * EPSF) * n;
    icn[k] = 1.f / csn;
    run += cl[j];
  }
  if (t == 63) offsets[1024] = run;
}

// ---------------- scatter row ids into cluster-ordered list (+ zero sums) ----------
__global__ void scatter_kernel(const int* __restrict__ ind, unsigned int* __restrict__ cursor,
                               int* __restrict__ rowlist, float4* __restrict__ sums4) {
  int n = blockIdx.x * 256 + threadIdx.x;
  sums4[n] = (float4){0.f, 0.f, 0.f, 0.f};  // 65536 x 16 B = 1 MB
  int k = ind[n];
  unsigned int pos = atomicAdd(&cursor[k], 1u);
  rowlist[pos] = n;
}

// ---------------- balanced segment-sum: position-partitioned + boundary flush ----
__global__ __launch_bounds__(256) void sumflush_kernel(
    const _Float16* __restrict__ xh, const int* __restrict__ rowlist,
    const int* __restrict__ ind, float* __restrict__ sums) {
  __shared__ int rl[64];
  __shared__ int kl[64];
  const int t = threadIdx.x;
  const int sub = t >> 6, lane = t & 63;
  const int p0 = blockIdx.x * 64;
  if (t < 64) {
    int r = rowlist[p0 + t];
    rl[t] = r;
    kl[t] = ind[r];
  }
  __syncthreads();
  float a0 = 0.f, a1 = 0.f, a2 = 0.f, a3 = 0.f;
  int curk = kl[sub * 16];
#pragma unroll
  for (int i = 0; i < 16; ++i) {
    int p = sub * 16 + i;
    int k = kl[p];
    if (k != curk) {  // wave-uniform branch
      float* dst = &sums[(size_t)curk * 256 + lane * 4];
      atomicAdd(&dst[0], a0);
      atomicAdd(&dst[1], a1);
      atomicAdd(&dst[2], a2);
      atomicAdd(&dst[3], a3);
      a0 = a1 = a2 = a3 = 0.f;
      curk = k;
    }
    int r = rl[p];
    uint2 vh = *(const uint2*)&((const unsigned int*)xh)[(size_t)r * 128 + lane * 2];
    a0 += h_val((unsigned short)(vh.x & 0xFFFF));
    a1 += h_val((unsigned short)(vh.x >> 16));
    a2 += h_val((unsigned short)(vh.y & 0xFFFF));
    a3 += h_val((unsigned short)(vh.y >> 16));
  }
  float* dst = &sums[(size_t)curk * 256 + lane * 4];
  atomicAdd(&dst[0], a0);
  atomicAdd(&dst[1], a1);
  atomicAdd(&dst[2], a2);
  atomicAdd(&dst[3], a3);
}

// ---------------- centroid EMA + scale, [k][f] -> [f][k] transpose ----------------
__global__ __launch_bounds__(256) void newcentT_kernel(
    const float* __restrict__ sums, const float* __restrict__ avg,
    const float* __restrict__ icn, float* __restrict__ nc) {
  __shared__ float tl[32][33];
  const int t = threadIdx.x;
  const int k0 = (blockIdx.x & 31) * 32, f0 = (blockIdx.x >> 5) * 32;
#pragma unroll
  for (int i = 0; i < 4; ++i) {
    int ki = (t >> 5) + i * 8, fi = t & 31;
    tl[ki][fi] = sums[(size_t)(k0 + ki) * 256 + f0 + fi];
  }
  __syncthreads();
#pragma unroll
  for (int i = 0; i < 4; ++i) {
    int fi = (t >> 5) + i * 8, ki = t & 31;
    size_t idx = (size_t)(f0 + fi) * 1024 + k0 + ki;
    nc[idx] = (DECAY * avg[idx] + (1.f - DECAY) * tl[ki][fi]) * icn[k0 + ki];
  }
}

// ---------------- gather output (vectorized): out[b][c][h][w] = nc[c][ind] ---------
__global__ void gather_kernel(const float* __restrict__ nc, const int* __restrict__ ind,
                              float* __restrict__ out) {
  __shared__ int ip[1024];
  int b = blockIdx.x >> 3;
  int cg = (blockIdx.x & 7) * 32;
  int t = threadIdx.x;
#pragma unroll
  for (int j = 0; j < 4; ++j) {
    int p = t + j * 256;                 // p = h*32 + w
    int r = ((p & 31) << 5) | (p >> 5);  // r = w*32 + h
    ip[p] = ind[(b << 10) + r];
  }
  __syncthreads();
  const int p0 = t * 4;
  const int i0 = ip[p0], i1 = ip[p0 + 1], i2 = ip[p0 + 2], i3 = ip[p0 + 3];
  for (int c = cg; c < cg + 32; ++c) {
    const float* row = nc + (size_t)c * 1024;
    float4 v = {row[i0], row[i1], row[i2], row[i3]};
    *(float4*)&out[((size_t)(b * 256 + c) << 10) + p0] = v;
  }
}

extern "C" void kernel_launch(void* const* d_in, const int* in_sizes, int n_in,
                              void* d_out, int out_size, void* d_ws, size_t ws_size,
                              hipStream_t stream) {
  const float* x = (const float*)d_in[0];
  const float* cent = (const float*)d_in[1];
  const float* cs = (const float*)d_in[2];
  const float* avg = (const float*)d_in[3];
  float* out = (float*)d_out;

  char* ws = (char*)d_ws;
  _Float16* xh = (_Float16*)ws;                              // [0, 33554432)   32 MB
  _Float16* ctp = (_Float16*)(ws + 33554432);                // [33554432, 34078720) 512 KB
  float* nc = (float*)(ws + 33554432);                       // [33554432, 34603008) 1 MB (aliases ctp; ctp dead by newcentT)
  unsigned int* counts = (unsigned int*)(ws + 34603008);     // 4 KB
  unsigned int* flagcnt = (unsigned int*)(ws + 34607104);    // 4 KB
  float* csqv = (float*)(ws + 34611200);                     // 4 KB
  float* icn = (float*)(ws + 34615296);                      // 4 KB
  unsigned int* offsets = (unsigned int*)(ws + 34619392);    // 8 KB (1025 used)
  unsigned int* cursor = (unsigned int*)(ws + 34627584);     // 4 KB
  int* ind = (int*)(ws + 34631680);                          // [34631680, 34893824) 256 KB
  int* flaglist = (int*)(ws + 34893824);                     // [34893824, 35155968) 256 KB (aliases rowlist)
  int* rowlist = (int*)(ws + 34893824);
  float* sums = (float*)(ws + 35155968);                     // [35155968, 36204544) 1 MB — PAST rowlist end (R12 bug: overlapped)

  centT_kernel<<<256, 256, 0, stream>>>(cent, ctp, csqv, counts, flagcnt);
  transpose_kernel<<<4096, 256, 0, stream>>>(x, xh);
  mfma_argmin_kernel<<<1024, 256, 0, stream>>>(xh, ctp, csqv, ind, flaglist, flagcnt, counts);
  fixup_kernel<<<256, 256, 0, stream>>>(x, cent, csqv, flaglist, flagcnt, ind, counts);
  csnorm_scan_kernel<<<1, 64, 0, stream>>>(cs, counts, icn, offsets, cursor);
  scatter_kernel<<<256, 256, 0, stream>>>(ind, cursor, rowlist, (float4*)sums);
  sumflush_kernel<<<1024, 256, 0, stream>>>(xh, rowlist, ind, sums);
  newcentT_kernel<<<256, 256, 0, stream>>>(sums, avg, icn, nc);
  gather_kernel<<<512, 256, 0, stream>>>(nc, ind, out);
}

// Round 16
// 264.492 us; speedup vs baseline: 1.4924x; 1.0028x over previous
//
#include <hip/hip_runtime.h>

// x: [64, 256, 32, 32] f32 ; centroids: [256, 1024] ; cluster_size: [1024] ;
// centroids_avg: [256, 1024]
// N = 65536 rows, F = 256, K = 1024.  xf row n = (b*32 + w)*32 + h

#define DECAY 0.99f
#define EPSF 1e-5f
#define DELTA 0.05f

typedef _Float16 f16x8 __attribute__((ext_vector_type(8)));
typedef float f32x4 __attribute__((ext_vector_type(4)));

static __device__ __forceinline__ unsigned short h_bits(_Float16 h) {
  return __builtin_bit_cast(unsigned short, h);
}
static __device__ __forceinline__ float h_val(unsigned short u) {
  return (float)__builtin_bit_cast(_Float16, u);
}

// ---------------- centroids -> packed fp16 B-frag layout + fused csq + zeroing ----
// ctp element for (k, f): colt=k>>4, lr=k&15, ks=f>>5, lg=(f>>3)&3, e=f&7
// half index = colt*4096 + ks*512 + lr*32 + lg*8 + e
// Blocks with f0==0 (bid<32) also compute csq for their 32 k (deterministic order).
// Block 32 zeroes counts+flagcnt.
__global__ void centT_kernel(const float* __restrict__ cent, _Float16* __restrict__ ctp,
                             float* __restrict__ csq, unsigned int* __restrict__ counts,
                             unsigned int* __restrict__ flagcnt) {
  __shared__ float tl[32][33];
  const int bid = blockIdx.x;
  const int f0 = (bid >> 5) * 32, k0 = (bid & 31) * 32;
  const int t = threadIdx.x;
#pragma unroll
  for (int i = 0; i < 4; ++i) {
    int fi = (t >> 5) + i * 8, ki = t & 31;
    tl[fi][ki] = cent[(size_t)(f0 + fi) * 1024 + k0 + ki];
  }
  __syncthreads();
#pragma unroll
  for (int i = 0; i < 4; ++i) {
    int ki = (t >> 5) + i * 8, fi = t & 31;
    int k = k0 + ki, f = f0 + fi;
    _Float16 h = (_Float16)tl[fi][ki];
    size_t idx = (size_t)(k >> 4) * 4096 + (size_t)(f >> 5) * 512 +
                 (size_t)(k & 15) * 32 + (size_t)((f >> 3) & 3) * 8 + (f & 7);
    ctp[idx] = h;
  }
  if (bid < 32) {  // full-column csq for k0..k0+31, fixed summation order
    __shared__ float red[8][32];
    const int kk = k0 + (t & 31);
    const int fg = t >> 5;
    float s = 0.f;
    for (int f = fg * 32; f < fg * 32 + 32; ++f) {
      float v = cent[(size_t)f * 1024 + kk];
      s += v * v;
    }
    red[fg][t & 31] = s;
    __syncthreads();
    if (t < 32) {
      float tot = 0.f;
#pragma unroll
      for (int g = 0; g < 8; ++g) tot += red[g][t];
      csq[k0 + t] = tot;
    }
  }
  if (bid == 32) {
    counts[t] = 0u;
    counts[t + 256] = 0u;
    counts[t + 512] = 0u;
    counts[t + 768] = 0u;
    if (t == 0) *flagcnt = 0u;
  }
}

// ---------------- transpose x -> xh fp16 [65536][256], vectorized ----------------
// Word/channel mapping identical to R13's scalar version: word ct*32+m of row r
// packs channels ct*64+2m, ct*64+2m+1.
__global__ void transpose_kernel(const float* __restrict__ x, _Float16* __restrict__ xh) {
  __shared__ float tile[64][65];
  int bid = blockIdx.x;
  int pt = bid & 15, ct = (bid >> 4) & 3, b = bid >> 6;
  int c0 = ct * 64, p0 = pt * 64;
  int t = threadIdx.x;
#pragma unroll
  for (int i = 0; i < 4; ++i) {
    int idx = t + i * 256;            // 1024 float4 loads: 64 c x 16 pixel-quads
    int ci = idx >> 4, pq = idx & 15;
    float4 v = *(const float4*)&x[((size_t)(b * 256 + c0 + ci) << 10) + p0 + pq * 4];
    tile[ci][pq * 4 + 0] = v.x;
    tile[ci][pq * 4 + 1] = v.y;
    tile[ci][pq * 4 + 2] = v.z;
    tile[ci][pq * 4 + 3] = v.w;
  }
  __syncthreads();
#pragma unroll
  for (int i = 0; i < 2; ++i) {
    int idx = t + i * 256;            // 512 uint4 stores: 64 p x 8 channel-octets
    int pi = idx >> 3, cg = idx & 7;
    int p = p0 + pi;
    int r = ((p & 31) << 5) | (p >> 5);
    unsigned int wd[4];
#pragma unroll
    for (int j = 0; j < 4; ++j) {
      float v0 = tile[cg * 8 + j * 2][pi];
      float v1 = tile[cg * 8 + j * 2 + 1][pi];
      wd[j] = (unsigned int)h_bits((_Float16)v0) |
              ((unsigned int)h_bits((_Float16)v1) << 16);
    }
    uint4 u = {wd[0], wd[1], wd[2], wd[3]};
    *(uint4*)((unsigned int*)xh + (size_t)((b << 10) + r) * 128 + ct * 32 + cg * 4) = u;
  }
}

// ---------------- MFMA distance + argmin + 2nd-best margin (R11/R13, frozen) -------
// 64-row blocks, launch_bounds (256,2): measured VGPR 108, NO spill — the counted
// vmcnt(4) discipline requires a spill-free K-loop (spill ops count in vmcnt).
__global__ __launch_bounds__(256, 2) void mfma_argmin_kernel(
    const _Float16* __restrict__ xh, const _Float16* __restrict__ ctp,
    const float* __restrict__ csq, int* __restrict__ ind,
    int* __restrict__ flaglist, unsigned int* __restrict__ flagcnt,
    unsigned int* __restrict__ counts) {
  __shared__ _Float16 Ah[64 * 256];         // 32 KB, 512 B/row, XOR-swizzled
  __shared__ _Float16 Bst[4 * 2 * 4 * 512]; // 32 KB: [wave][parity][ct][512 halfs]
  __shared__ float csql[1024];
  __shared__ float red1[4][64], red2[4][64];
  __shared__ int redk[4][64];
  const int t = threadIdx.x;
  const int lane = t & 63, w = t >> 6;
  const int lr = lane & 15, lg = lane >> 4;
  const int n0 = blockIdx.x * 64;

#pragma unroll
  for (int i = 0; i < 4; ++i) csql[t + i * 256] = csq[t + i * 256];
#pragma unroll
  for (int i = 0; i < 8; ++i) {
    int idx = t + i * 256;            // 2048 = 64 rows x 32 16B-chunks
    int row = idx >> 5, c16 = (idx & 31) * 16;
    int sw = c16 ^ ((row & 7) << 4);
    *(f16x8*)((char*)Ah + row * 512 + sw) =
        *(const f16x8*)((const char*)xh + (size_t)(n0 + row) * 512 + c16);
  }
  __syncthreads();   // drains vmcnt: staging loads retired before DMA counting starts

  float b1[4][4], b2v[4][4];
  int bk[4][4];
#pragma unroll
  for (int rt = 0; rt < 4; ++rt)
#pragma unroll
    for (int rg = 0; rg < 4; ++rg) { b1[rt][rg] = 3.4e38f; b2v[rt][rg] = 3.4e38f; bk[rt][rg] = 0; }

  const int swz = (lr & 7) << 4;
  const int boffh = (lr * 4 + lg) * 8;      // lane's frag (halfs) within a 1KB chunk
  const size_t lgo = (size_t)lane * 16;     // DMA: lane's byte offset within a chunk
  _Float16* bw = &Bst[w * 4096];            // wave-private 8 KB region

#define DMA4(CHB, KS, P)                                                              \
  do {                                                                                \
    const char* g_ = (const char*)ctp + (CHB) + (size_t)(KS) * 1024 + lgo;            \
    _Float16* l_ = bw + (P) * 2048;                                                   \
    __builtin_amdgcn_global_load_lds(                                                 \
        (const __attribute__((address_space(1))) unsigned int*)(g_),                  \
        (__attribute__((address_space(3))) unsigned int*)(l_), 16, 0, 0);             \
    __builtin_amdgcn_global_load_lds(                                                 \
        (const __attribute__((address_space(1))) unsigned int*)(g_ + 8192),           \
        (__attribute__((address_space(3))) unsigned int*)(l_ + 512), 16, 0, 0);       \
    __builtin_amdgcn_global_load_lds(                                                 \
        (const __attribute__((address_space(1))) unsigned int*)(g_ + 16384),          \
        (__attribute__((address_space(3))) unsigned int*)(l_ + 1024), 16, 0, 0);      \
    __builtin_amdgcn_global_load_lds(                                                 \
        (const __attribute__((address_space(1))) unsigned int*)(g_ + 24576),          \
        (__attribute__((address_space(3))) unsigned int*)(l_ + 1536), 16, 0, 0);      \
  } while (0)

#define KSHALF(KS, P, WN)                                                             \
  do {                                                                                \
    asm volatile("s_waitcnt vmcnt(" WN ")" ::: "memory");                             \
    __builtin_amdgcn_sched_barrier(0);                                                \
    const _Float16* bp_ = bw + (P) * 2048 + boffh;                                    \
    f16x8 q0 = *(const f16x8*)(bp_);                                                  \
    f16x8 q1 = *(const f16x8*)(bp_ + 512);                                            \
    f16x8 q2 = *(const f16x8*)(bp_ + 1024);                                           \
    f16x8 q3 = *(const f16x8*)(bp_ + 1536);                                           \
    const char* ap_ = (const char*)Ah + lr * 512 + (((KS) * 64 + lg * 16) ^ swz);     \
    f16x8 p0 = *(const f16x8*)(ap_);                                                  \
    f16x8 p1 = *(const f16x8*)(ap_ + 8192);                                           \
    f16x8 p2 = *(const f16x8*)(ap_ + 16384);                                          \
    f16x8 p3 = *(const f16x8*)(ap_ + 24576);                                          \
    acc[0][0] = __builtin_amdgcn_mfma_f32_16x16x32_f16(p0, q0, acc[0][0], 0, 0, 0);   \
    acc[0][1] = __builtin_amdgcn_mfma_f32_16x16x32_f16(p1, q0, acc[0][1], 0, 0, 0);   \
    acc[0][2] = __builtin_amdgcn_mfma_f32_16x16x32_f16(p2, q0, acc[0][2], 0, 0, 0);   \
    acc[0][3] = __builtin_amdgcn_mfma_f32_16x16x32_f16(p3, q0, acc[0][3], 0, 0, 0);   \
    acc[1][0] = __builtin_amdgcn_mfma_f32_16x16x32_f16(p0, q1, acc[1][0], 0, 0, 0);   \
    acc[1][1] = __builtin_amdgcn_mfma_f32_16x16x32_f16(p1, q1, acc[1][1], 0, 0, 0);   \
    acc[1][2] = __builtin_amdgcn_mfma_f32_16x16x32_f16(p2, q1, acc[1][2], 0, 0, 0);   \
    acc[1][3] = __builtin_amdgcn_mfma_f32_16x16x32_f16(p3, q1, acc[1][3], 0, 0, 0);   \
    acc[2][0] = __builtin_amdgcn_mfma_f32_16x16x32_f16(p0, q2, acc[2][0], 0, 0, 0);   \
    acc[2][1] = __builtin_amdgcn_mfma_f32_16x16x32_f16(p1, q2, acc[2][1], 0, 0, 0);   \
    acc[2][2] = __builtin_amdgcn_mfma_f32_16x16x32_f16(p2, q2, acc[2][2], 0, 0, 0);   \
    acc[2][3] = __builtin_amdgcn_mfma_f32_16x16x32_f16(p3, q2, acc[2][3], 0, 0, 0);   \
    acc[3][0] = __builtin_amdgcn_mfma_f32_16x16x32_f16(p0, q3, acc[3][0], 0, 0, 0);   \
    acc[3][1] = __builtin_amdgcn_mfma_f32_16x16x32_f16(p1, q3, acc[3][1], 0, 0, 0);   \
    acc[3][2] = __builtin_amdgcn_mfma_f32_16x16x32_f16(p2, q3, acc[3][2], 0, 0, 0);   \
    acc[3][3] = __builtin_amdgcn_mfma_f32_16x16x32_f16(p3, q3, acc[3][3], 0, 0, 0);   \
  } while (0)

  size_t chb = (size_t)w * 131072;  // wave's ctp byte base; ch adds 32768
  DMA4(chb, 0, 0);
  DMA4(chb, 1, 1);
#pragma unroll 1
  for (int ch = 0; ch < 4; ++ch) {
    const int ccb = w * 256 + ch * 64;
    f32x4 acc[4][4];                // [ct][rt]
#pragma unroll
    for (int ct = 0; ct < 4; ++ct)
#pragma unroll
      for (int rt = 0; rt < 4; ++rt) acc[ct][rt] = (f32x4){0.f, 0.f, 0.f, 0.f};

    KSHALF(0, 0, "4");  DMA4(chb, 2, 0);
    KSHALF(1, 1, "4");  DMA4(chb, 3, 1);
    KSHALF(2, 0, "4");  DMA4(chb, 4, 0);
    KSHALF(3, 1, "4");  DMA4(chb, 5, 1);
    KSHALF(4, 0, "4");  DMA4(chb, 6, 0);
    KSHALF(5, 1, "4");  DMA4(chb, 7, 1);
    KSHALF(6, 0, "4");
    if (ch < 3) {
      DMA4(chb + 32768, 0, 0);
      KSHALF(7, 1, "4");
      DMA4(chb + 32768, 1, 1);
    } else {
      KSHALF(7, 1, "0");
    }

#pragma unroll
    for (int ct = 0; ct < 4; ++ct) {
      const int col = ccb + ct * 16 + lr;
      const float cq = csql[col];
#pragma unroll
      for (int rt = 0; rt < 4; ++rt)
#pragma unroll
        for (int rg = 0; rg < 4; ++rg) {
          float d = cq - 2.f * acc[ct][rt][rg];
          if (d < b1[rt][rg]) {
            b2v[rt][rg] = b1[rt][rg];
            b1[rt][rg] = d;
            bk[rt][rg] = col;
          } else if (d < b2v[rt][rg]) {
            b2v[rt][rg] = d;
          }
        }
    }
    chb += 32768;
  }
#undef DMA4
#undef KSHALF

#pragma unroll
  for (int rt = 0; rt < 4; ++rt)
#pragma unroll
    for (int rg = 0; rg < 4; ++rg) {
      float v1 = b1[rt][rg], v2 = b2v[rt][rg];
      int kk = bk[rt][rg];
#pragma unroll
      for (int off = 8; off >= 1; off >>= 1) {
        float o1 = __shfl_xor(v1, off);
        int ok = __shfl_xor(kk, off);
        float o2 = __shfl_xor(v2, off);
        float nb2 = fminf(fmaxf(v1, o1), fminf(v2, o2));
        if (o1 < v1 || (o1 == v1 && ok < kk)) { v1 = o1; kk = ok; }
        v2 = nb2;
      }
      if (lr == 0) {
        int row = rt * 16 + lg * 4 + rg;
        red1[w][row] = v1;
        redk[w][row] = kk;
        red2[w][row] = v2;
      }
    }
  __syncthreads();
  if (t < 64) {
    float v1 = red1[0][t], v2 = red2[0][t];
    int kk = redk[0][t];
#pragma unroll
    for (int wi = 1; wi < 4; ++wi) {
      float o1 = red1[wi][t], o2 = red2[wi][t];
      int ok = redk[wi][t];
      float nb2 = fminf(fmaxf(v1, o1), fminf(v2, o2));
      if (o1 < v1 || (o1 == v1 && ok < kk)) { v1 = o1; kk = ok; }
      v2 = nb2;
    }
    ind[n0 + t] = kk;
    atomicAdd(&counts[kk], 1u);
    if (v2 - v1 < DELTA) {
      unsigned int p = atomicAdd(flagcnt, 1u);
      flaglist[p] = n0 + t;
    }
  }
}

// ---------------- exact fp32 re-argmin, batched 4 rows per cent-pass ----------------
__global__ __launch_bounds__(256) void fixup_kernel(
    const float* __restrict__ x, const float* __restrict__ cent,
    const float* __restrict__ csq, const int* __restrict__ flaglist,
    const unsigned int* __restrict__ flagcnt, int* __restrict__ ind,
    unsigned int* __restrict__ counts) {
  const int t = threadIdx.x;
  const int nf = (int)*flagcnt;
  __shared__ float xrow[4][256];
  __shared__ int rows[4];
  __shared__ float rv[256];
  __shared__ int rk[256];
  for (int base = blockIdx.x * 4; base < nf; base += gridDim.x * 4) {
    const int cnt = min(4, nf - base);
    __syncthreads();
    if (t < 4) rows[t] = flaglist[base + (t < cnt ? t : 0)];
    __syncthreads();
#pragma unroll
    for (int j = 0; j < 4; ++j) {
      int row = rows[j];
      int b = row >> 10, r = row & 1023, wq = r >> 5, h = r & 31;
      xrow[j][t] = x[((size_t)(b * 256 + t) << 10) + h * 32 + wq];  // exact fp32
    }
    __syncthreads();
    float a[4][4];
#pragma unroll
    for (int j = 0; j < 4; ++j)
#pragma unroll
      for (int q = 0; q < 4; ++q) a[j][q] = 0.f;
#pragma unroll 4
    for (int f = 0; f < 256; ++f) {
      const float* cr = cent + (size_t)f * 1024 + t;
      float c0 = cr[0], c1 = cr[256], c2 = cr[512], c3 = cr[768];
#pragma unroll
      for (int j = 0; j < 4; ++j) {
        float xv = xrow[j][f];
        a[j][0] += xv * c0;
        a[j][1] += xv * c1;
        a[j][2] += xv * c2;
        a[j][3] += xv * c3;
      }
    }
    for (int j = 0; j < cnt; ++j) {
      float bd = csq[t] - 2.f * a[j][0];
      int bkk = t;
      float d1 = csq[t + 256] - 2.f * a[j][1];
      if (d1 < bd) { bd = d1; bkk = t + 256; }
      float d2 = csq[t + 512] - 2.f * a[j][2];
      if (d2 < bd) { bd = d2; bkk = t + 512; }
      float d3 = csq[t + 768] - 2.f * a[j][3];
      if (d3 < bd) { bd = d3; bkk = t + 768; }
      rv[t] = bd;
      rk[t] = bkk;
      __syncthreads();
      for (int off = 128; off >= 1; off >>= 1) {
        if (t < off) {
          float ov = rv[t + off];
          int ok = rk[t + off];
          if (ov < rv[t] || (ov == rv[t] && ok < rk[t])) { rv[t] = ov; rk[t] = ok; }
        }
        __syncthreads();
      }
      if (t == 0) {
        int newk = rk[0], row = rows[j], oldk = ind[row];
        if (newk != oldk) {
          ind[row] = newk;
          atomicAdd(&counts[oldk], 0xFFFFFFFFu);  // -1
          atomicAdd(&counts[newk], 1u);
        }
      }
      __syncthreads();
    }
  }
}

// ---------------- single-wave: cluster-size EMA/Laplace norm + exclusive scan ----
__global__ __launch_bounds__(64) void csnorm_scan_kernel(
    const float* __restrict__ cs, const unsigned int* __restrict__ counts,
    float* __restrict__ icn, unsigned int* __restrict__ offsets,
    unsigned int* __restrict__ cursor) {
  const int t = threadIdx.x;  // 0..63, each owns 16 clusters
  unsigned int cl[16];
  float csl[16];
  unsigned int s = 0;
  float css = 0.f;
#pragma unroll
  for (int j = 0; j < 16; ++j) {
    cl[j] = counts[t * 16 + j];
    s += cl[j];
    csl[j] = cs[t * 16 + j];
    css += csl[j];
  }
  unsigned int incl = s;
#pragma unroll
  for (int off = 1; off < 64; off <<= 1) {
    unsigned int v = __shfl_up(incl, off);
    if (t >= off) incl += v;
  }
  unsigned int run = incl - s;  // exclusive prefix
  float tot = css;
#pragma unroll
  for (int off = 32; off >= 1; off >>= 1) tot += __shfl_xor(tot, off);
  const float n = DECAY * tot + (1.f - DECAY) * 65536.f;  // counts sum = N
#pragma unroll
  for (int j = 0; j < 16; ++j) {
    int k = t * 16 + j;
    offsets[k] = run;
    cursor[k] = run;
    float ncs = DECAY * csl[j] + (1.f - DECAY) * (float)cl[j];
    float csn = (ncs + EPSF) / (n + 1024.f * EPSF) * n;
    icn[k] = 1.f / csn;
    run += cl[j];
  }
  if (t == 63) offsets[1024] = run;
}

// ---------------- scatter row ids into cluster-ordered list (+ zero sums) ----------
__global__ void scatter_kernel(const int* __restrict__ ind, unsigned int* __restrict__ cursor,
                               int* __restrict__ rowlist, float4* __restrict__ sums4) {
  int n = blockIdx.x * 256 + threadIdx.x;
  sums4[n] = (float4){0.f, 0.f, 0.f, 0.f};  // 65536 x 16 B = 1 MB
  int k = ind[n];
  unsigned int pos = atomicAdd(&cursor[k], 1u);
  rowlist[pos] = n;
}

// ---------------- balanced segment-sum: position-partitioned + boundary flush ----
__global__ __launch_bounds__(256) void sumflush_kernel(
    const _Float16* __restrict__ xh, const int* __restrict__ rowlist,
    const int* __restrict__ ind, float* __restrict__ sums) {
  __shared__ int rl[64];
  __shared__ int kl[64];
  const int t = threadIdx.x;
  const int sub = t >> 6, lane = t & 63;
  const int p0 = blockIdx.x * 64;
  if (t < 64) {
    int r = rowlist[p0 + t];
    rl[t] = r;
    kl[t] = ind[r];
  }
  __syncthreads();
  float a0 = 0.f, a1 = 0.f, a2 = 0.f, a3 = 0.f;
  int curk = kl[sub * 16];
#pragma unroll
  for (int i = 0; i < 16; ++i) {
    int p = sub * 16 + i;
    int k = kl[p];
    if (k != curk) {  // wave-uniform branch
      float* dst = &sums[(size_t)curk * 256 + lane * 4];
      atomicAdd(&dst[0], a0);
      atomicAdd(&dst[1], a1);
      atomicAdd(&dst[2], a2);
      atomicAdd(&dst[3], a3);
      a0 = a1 = a2 = a3 = 0.f;
      curk = k;
    }
    int r = rl[p];
    uint2 vh = *(const uint2*)&((const unsigned int*)xh)[(size_t)r * 128 + lane * 2];
    a0 += h_val((unsigned short)(vh.x & 0xFFFF));
    a1 += h_val((unsigned short)(vh.x >> 16));
    a2 += h_val((unsigned short)(vh.y & 0xFFFF));
    a3 += h_val((unsigned short)(vh.y >> 16));
  }
  float* dst = &sums[(size_t)curk * 256 + lane * 4];
  atomicAdd(&dst[0], a0);
  atomicAdd(&dst[1], a1);
  atomicAdd(&dst[2], a2);
  atomicAdd(&dst[3], a3);
}

// ---------------- centroid EMA + scale, [k][f] -> [f][k] transpose ----------------
__global__ __launch_bounds__(256) void newcentT_kernel(
    const float* __restrict__ sums, const float* __restrict__ avg,
    const float* __restrict__ icn, float* __restrict__ nc) {
  __shared__ float tl[32][33];
  const int t = threadIdx.x;
  const int k0 = (blockIdx.x & 31) * 32, f0 = (blockIdx.x >> 5) * 32;
#pragma unroll
  for (int i = 0; i < 4; ++i) {
    int ki = (t >> 5) + i * 8, fi = t & 31;
    tl[ki][fi] = sums[(size_t)(k0 + ki) * 256 + f0 + fi];
  }
  __syncthreads();
#pragma unroll
  for (int i = 0; i < 4; ++i) {
    int fi = (t >> 5) + i * 8, ki = t & 31;
    size_t idx = (size_t)(f0 + fi) * 1024 + k0 + ki;
    nc[idx] = (DECAY * avg[idx] + (1.f - DECAY) * tl[ki][fi]) * icn[k0 + ki];
  }
}

// ---------------- gather output (vectorized): out[b][c][h][w] = nc[c][ind] ---------
__global__ void gather_kernel(const float* __restrict__ nc, const int* __restrict__ ind,
                              float* __restrict__ out) {
  __shared__ int ip[1024];
  int b = blockIdx.x >> 3;
  int cg = (blockIdx.x & 7) * 32;
  int t = threadIdx.x;
#pragma unroll
  for (int j = 0; j < 4; ++j) {
    int p = t + j * 256;                 // p = h*32 + w
    int r = ((p & 31) << 5) | (p >> 5);  // r = w*32 + h
    ip[p] = ind[(b << 10) + r];
  }
  __syncthreads();
  const int p0 = t * 4;
  const int i0 = ip[p0], i1 = ip[p0 + 1], i2 = ip[p0 + 2], i3 = ip[p0 + 3];
  for (int c = cg; c < cg + 32; ++c) {
    const float* row = nc + (size_t)c * 1024;
    float4 v = {row[i0], row[i1], row[i2], row[i3]};
    *(float4*)&out[((size_t)(b * 256 + c) << 10) + p0] = v;
  }
}

extern "C" void kernel_launch(void* const* d_in, const int* in_sizes, int n_in,
                              void* d_out, int out_size, void* d_ws, size_t ws_size,
                              hipStream_t stream) {
  const float* x = (const float*)d_in[0];
  const float* cent = (const float*)d_in[1];
  const float* cs = (const float*)d_in[2];
  const float* avg = (const float*)d_in[3];
  float* out = (float*)d_out;

  char* ws = (char*)d_ws;
  _Float16* xh = (_Float16*)ws;                              // [0, 33554432)
  _Float16* ctp = (_Float16*)(ws + 33554432);                // 512 KB
  float* nc = (float*)(ws + 33554432);                       // 1 MB (aliases ctp; ctp dead by newcentT)
  unsigned int* counts = (unsigned int*)(ws + 34603008);     // 4 KB
  unsigned int* flagcnt = (unsigned int*)(ws + 34607104);    // 4 KB
  float* csqv = (float*)(ws + 34611200);                     // 4 KB
  float* icn = (float*)(ws + 34615296);                      // 4 KB
  unsigned int* offsets = (unsigned int*)(ws + 34619392);    // 8 KB (1025 used)
  unsigned int* cursor = (unsigned int*)(ws + 34627584);     // 4 KB
  int* ind = (int*)(ws + 34631680);                          // [.., 34893824) 256 KB
  int* flaglist = (int*)(ws + 34893824);                     // [.., 35155968) 256 KB (aliases rowlist)
  int* rowlist = (int*)(ws + 34893824);
  float* sums = (float*)(ws + 35155968);                     // [.., 36204544) 1 MB

  centT_kernel<<<256, 256, 0, stream>>>(cent, ctp, csqv, counts, flagcnt);
  transpose_kernel<<<4096, 256, 0, stream>>>(x, xh);
  mfma_argmin_kernel<<<1024, 256, 0, stream>>>(xh, ctp, csqv, ind, flaglist, flagcnt, counts);
  fixup_kernel<<<256, 256, 0, stream>>>(x, cent, csqv, flaglist, flagcnt, ind, counts);
  csnorm_scan_kernel<<<1, 64, 0, stream>>>(cs, counts, icn, offsets, cursor);
  scatter_kernel<<<256, 256, 0, stream>>>(ind, cursor, rowlist, (float4*)sums);
  sumflush_kernel<<<1024, 256, 0, stream>>>(xh, rowlist, ind, sums);
  newcentT_kernel<<<256, 256, 0, stream>>>(sums, avg, icn, nc);
  gather_kernel<<<512, 256, 0, stream>>>(nc, ind, out);
}